// Round 5
// baseline (506.691 us; speedup 1.0000x reference)
//
#include <hip/hip_runtime.h>
#include <hip/hip_fp16.h>
#include <math.h>

#define IN_F 50
#define HID 64
#define NC 12
#define LN_EPS 1e-5f

// ---------------- CSR construction ----------------
// Edge record: one 8B word = (edge_attr bits << 32) | src  -- single random
// store per edge (was 2 stores into 2 arrays -> 13x write amplification).

__global__ void count_kernel(const int* __restrict__ dst, int* __restrict__ cnt, int e) {
  int i = blockIdx.x * blockDim.x + threadIdx.x;
  if (i < e) atomicAdd(&cnt[dst[i]], 1);
}

// ---- 3-phase exclusive scan over n counts (chunk = 1024 per block) ----

__global__ __launch_bounds__(256) void scan_reduce_kernel(const int* __restrict__ cnt,
                                                          int* __restrict__ part, int n) {
  int base = blockIdx.x * 1024;
  int sum = 0;
  for (int i = threadIdx.x; i < 1024; i += 256) {
    int g = base + i;
    if (g < n) sum += cnt[g];
  }
#pragma unroll
  for (int off = 1; off < 64; off <<= 1) sum += __shfl_xor(sum, off);
  __shared__ int ws[4];
  if ((threadIdx.x & 63) == 0) ws[threadIdx.x >> 6] = sum;
  __syncthreads();
  if (threadIdx.x == 0) part[blockIdx.x] = ws[0] + ws[1] + ws[2] + ws[3];
}

__global__ void scan_part_kernel(int* __restrict__ part, int nb, int* __restrict__ total) {
  int lane = threadIdx.x;
  int orig = (lane < nb) ? part[lane] : 0;
  int v = orig;
#pragma unroll
  for (int off = 1; off < 64; off <<= 1) {
    int t = __shfl_up(v, off);
    if (lane >= off) v += t;
  }
  if (lane < nb) part[lane] = v - orig;   // exclusive
  if (lane == 63) *total = v;             // rowptr[n]
}

__global__ __launch_bounds__(256) void scan_apply_kernel(const int* __restrict__ cnt,
    const int* __restrict__ part, int* __restrict__ rowptr, int n) {
  int base = blockIdx.x * 1024;
  int t = threadIdx.x;
  int vals[4];
  int lsum = 0;
#pragma unroll
  for (int j = 0; j < 4; j++) {
    int g = base + t * 4 + j;
    vals[j] = (g < n) ? cnt[g] : 0;
    lsum += vals[j];
  }
  int v = lsum;
#pragma unroll
  for (int off = 1; off < 64; off <<= 1) {
    int tv = __shfl_up(v, off);
    if ((t & 63) >= off) v += tv;
  }
  __shared__ int wsum[4];
  if ((t & 63) == 63) wsum[t >> 6] = v;
  __syncthreads();
  int wbase = 0;
  int w = t >> 6;
#pragma unroll
  for (int j = 0; j < 4; j++) if (j < w) wbase += wsum[j];
  int excl = v - lsum + wbase + part[blockIdx.x];
#pragma unroll
  for (int j = 0; j < 4; j++) {
    int g = base + t * 4 + j;
    if (g < n) rowptr[g] = excl;
    excl += vals[j];
  }
}

__global__ void scatter_kernel(const int* __restrict__ src, const int* __restrict__ dst,
                               const float* __restrict__ ea, const int* __restrict__ rowptr,
                               int* __restrict__ fill,
                               unsigned long long* __restrict__ edges, int e) {
  int i = blockIdx.x * blockDim.x + threadIdx.x;
  if (i < e) {
    int d = dst[i];
    int pos = atomicSub(&fill[d], 1) - 1;   // cnt-1 .. 0 (order irrelevant)
    int slot = rowptr[d] + pos;
    unsigned long long rec =
        ((unsigned long long)__float_as_uint(ea[i]) << 32) | (unsigned int)src[i];
    __builtin_nontemporal_store(rec, &edges[slot]);
  }
}

// ---------------- generic tiled GEMM: C[M][*] = A[M][K] @ B[K][NCG*64] + bias ----------------
// WKV: cg==1 (k) and cg==2 (v) are written as fp16 into the interleaved gather
// buffer kvb[node][c4][k4|v4] instead of fp32 C (nothing reads fp32 k/v).

template<int K, int NCG, bool RELU, bool WKV>
__global__ __launch_bounds__(256, 3) void gemm_tiled(
    const float* __restrict__ A, int lda, int M,
    const float* __restrict__ B0, const float* __restrict__ B1,
    const float* __restrict__ B2, const float* __restrict__ B3,
    const float* __restrict__ g0, const float* __restrict__ g1,
    const float* __restrict__ g2, const float* __restrict__ g3,
    float* __restrict__ C, int ldc, __half* __restrict__ kvb)
{
  constexpr int NT = NCG * 64;
  __shared__ __align__(16) float Ash[K * 68];   // A^T: Ash[k*68 + row]
  __shared__ __align__(16) float Bsh[K * NT];
  __shared__ float bsh[NT];
  const int tid = threadIdx.x;
  const int row0 = blockIdx.x * 64;
  for (int i = tid; i < 64 * K; i += 256) {
    int r = i / K, k = i - r * K;
    int gr = row0 + r;
    Ash[k * 68 + r] = (gr < M) ? A[gr * lda + k] : 0.f;
  }
#pragma unroll
  for (int g = 0; g < NCG; g++) {
    int cg = blockIdx.y * NCG + g;
    const float* Bp = (cg == 0) ? B0 : (cg == 1) ? B1 : (cg == 2) ? B2 : B3;
    const float* bp = (cg == 0) ? g0 : (cg == 1) ? g1 : (cg == 2) ? g2 : g3;
    for (int i = tid; i < 64 * K; i += 256) {
      int k = i >> 6, c = i & 63;
      Bsh[k * NT + g * 64 + c] = Bp[k * 64 + c];
    }
    if (tid < 64) bsh[g * 64 + tid] = bp[tid];
  }
  __syncthreads();
  const int ty = tid >> 4, tx = tid & 15;
  float acc[4][NCG * 4];
#pragma unroll
  for (int i = 0; i < 4; i++)
#pragma unroll
    for (int g = 0; g < NCG; g++)
#pragma unroll
      for (int c = 0; c < 4; c++)
        acc[i][g * 4 + c] = bsh[g * 64 + tx * 4 + c];
#pragma unroll 4
  for (int k = 0; k < K; k++) {
    float4 av = *(const float4*)&Ash[k * 68 + ty * 4];
    float a_[4] = {av.x, av.y, av.z, av.w};
    float b_[NCG][4];
#pragma unroll
    for (int g = 0; g < NCG; g++) {
      float4 bv = *(const float4*)&Bsh[k * NT + g * 64 + tx * 4];
      b_[g][0] = bv.x; b_[g][1] = bv.y; b_[g][2] = bv.z; b_[g][3] = bv.w;
    }
#pragma unroll
    for (int i = 0; i < 4; i++)
#pragma unroll
      for (int g = 0; g < NCG; g++)
#pragma unroll
        for (int c = 0; c < 4; c++)
          acc[i][g * 4 + c] = fmaf(a_[i], b_[g][c], acc[i][g * 4 + c]);
  }
#pragma unroll
  for (int i = 0; i < 4; i++) {
    int r = row0 + ty * 4 + i;
    if (r < M) {
#pragma unroll
      for (int g = 0; g < NCG; g++) {
        int cg = blockIdx.y * NCG + g;
        if (WKV && (cg == 1 || cg == 2)) {
          __half hv[4];
#pragma unroll
          for (int c = 0; c < 4; c++) hv[c] = __float2half(acc[i][g * 4 + c]);
          *(ushort4*)&kvb[(size_t)r * 128 + tx * 8 + ((cg == 1) ? 0 : 4)] =
              *(ushort4*)hv;
        } else {
          float4 ov;
          ov.x = acc[i][g * 4 + 0]; ov.y = acc[i][g * 4 + 1];
          ov.z = acc[i][g * 4 + 2]; ov.w = acc[i][g * 4 + 3];
          if (RELU) {
            ov.x = fmaxf(ov.x, 0.f); ov.y = fmaxf(ov.y, 0.f);
            ov.z = fmaxf(ov.z, 0.f); ov.w = fmaxf(ov.w, 0.f);
          }
          *(float4*)&C[(size_t)r * ldc + cg * 64 + tx * 4] = ov;
        }
      }
    }
  }
}

// ---------------- fused attention + gate + LayerNorm ----------------
// qkvx layout: [node][256] = q(0:64) | unused | unused | xr(192:256)
// kvb layout:  [node][16 uint4]: lane c4 -> {k[c4*4..+3], v[c4*4..+3]} fp16
// edges: 8B packed (ea<<32 | src)

__global__ __launch_bounds__(256) void attn_post_kernel(
    const int* __restrict__ rowptr, const unsigned long long* __restrict__ edges,
    const float* __restrict__ qkvx, const uint4* __restrict__ kvb,
    const float* __restrict__ wedge, const float* __restrict__ wbeta,
    const float* __restrict__ lng, const float* __restrict__ lnb,
    float* __restrict__ h, int n)
{
  int lane = threadIdx.x & 63;
  int node = blockIdx.x * 4 + (threadIdx.x >> 6);
  if (node >= n) return;
  int grp = lane >> 4;
  int c4 = lane & 15;
  const float4* row4 = (const float4*)qkvx;   // 64 float4 per node row
  float4 q4 = row4[(size_t)node * 64 + c4];
  float4 we4 = ((const float4*)wedge)[c4];
  int s0 = rowptr[node], s1 = rowptr[node + 1];
  float m = -INFINITY, l = 0.f;
  float ax = 0.f, ay = 0.f, az = 0.f, aw = 0.f;
  for (int s = s0; s < s1; s += 4) {
    int es = s + grp;
    bool valid = es < s1;
    unsigned long long rec = valid ? edges[es] : 0ull;
    int srcn = (int)(unsigned int)(rec & 0xffffffffu);
    float a = __uint_as_float((unsigned int)(rec >> 32));
    float ex = a * we4.x, ey = a * we4.y, ez = a * we4.z, ew = a * we4.w;
    uint4 kv = kvb[(size_t)srcn * 16 + c4];          // one dwordx4 per edge
    float2 k01 = __half22float2(*(__half2*)&kv.x);
    float2 k23 = __half22float2(*(__half2*)&kv.y);
    float2 v01 = __half22float2(*(__half2*)&kv.z);
    float2 v23 = __half22float2(*(__half2*)&kv.w);
    float prod = q4.x * (k01.x + ex) + q4.y * (k01.y + ey)
               + q4.z * (k23.x + ez) + q4.w * (k23.y + ew);
    prod += __shfl_xor(prod, 1);
    prod += __shfl_xor(prod, 2);            // per-head 16-chan dot
    float alpha = valid ? prod * 0.25f : -INFINITY;
    float am = alpha;
    am = fmaxf(am, __shfl_xor(am, 16));
    am = fmaxf(am, __shfl_xor(am, 32));     // max over 4 edge slots
    float mnew = fmaxf(m, am);
    float msafe = (mnew == -INFINITY) ? 0.f : mnew;
    float scale = __expf(m - msafe);
    float p = __expf(alpha - msafe);
    float ps = p;
    ps += __shfl_xor(ps, 16);
    ps += __shfl_xor(ps, 32);
    l = l * scale + ps;
    ax = ax * scale + p * (v01.x + ex);
    ay = ay * scale + p * (v01.y + ey);
    az = az * scale + p * (v23.x + ez);
    aw = aw * scale + p * (v23.y + ew);
    m = mnew;
  }
  ax += __shfl_xor(ax, 16); ax += __shfl_xor(ax, 32);
  ay += __shfl_xor(ay, 16); ay += __shfl_xor(ay, 32);
  az += __shfl_xor(az, 16); az += __shfl_xor(az, 32);
  aw += __shfl_xor(aw, 16); aw += __shfl_xor(aw, 32);
  float inv = 1.f / (l + 1e-16f);
  float ox = ax * inv, oy = ay * inv, oz = az * inv, ow = aw * inv;
  float4 xr = row4[(size_t)node * 64 + 48 + c4];
  float4 hr = ((const float4*)h)[(size_t)node * 16 + c4];
  float4 w1 = ((const float4*)wbeta)[c4];
  float4 w2 = ((const float4*)wbeta)[16 + c4];
  float4 w3 = ((const float4*)wbeta)[32 + c4];
  float sv = ox * w1.x + oy * w1.y + oz * w1.z + ow * w1.w
           + xr.x * w2.x + xr.y * w2.y + xr.z * w2.z + xr.w * w2.w
           + (ox - xr.x) * w3.x + (oy - xr.y) * w3.y
           + (oz - xr.z) * w3.z + (ow - xr.w) * w3.w;
  sv += __shfl_xor(sv, 1); sv += __shfl_xor(sv, 2);
  sv += __shfl_xor(sv, 4); sv += __shfl_xor(sv, 8);
  float beta = 1.f / (1.f + __expf(-sv));
  float zx = beta * xr.x + (1.f - beta) * ox + hr.x;
  float zy = beta * xr.y + (1.f - beta) * oy + hr.y;
  float zz = beta * xr.z + (1.f - beta) * oz + hr.z;
  float zw = beta * xr.w + (1.f - beta) * ow + hr.w;
  float mu = zx + zy + zz + zw;
  mu += __shfl_xor(mu, 1); mu += __shfl_xor(mu, 2);
  mu += __shfl_xor(mu, 4); mu += __shfl_xor(mu, 8);
  mu *= (1.f / 64.f);
  float dx = zx - mu, dy = zy - mu, dz = zz - mu, dw = zw - mu;
  float var = dx * dx + dy * dy + dz * dz + dw * dw;
  var += __shfl_xor(var, 1); var += __shfl_xor(var, 2);
  var += __shfl_xor(var, 4); var += __shfl_xor(var, 8);
  var *= (1.f / 64.f);
  float rstd = rsqrtf(var + LN_EPS);
  float4 g4 = ((const float4*)lng)[c4];
  float4 b4 = ((const float4*)lnb)[c4];
  if (grp == 0) {
    float4 res;
    res.x = dx * rstd * g4.x + b4.x;
    res.y = dy * rstd * g4.y + b4.y;
    res.z = dz * rstd * g4.z + b4.z;
    res.w = dw * rstd * g4.w + b4.w;
    ((float4*)h)[(size_t)node * 16 + c4] = res;
  }
}

// ---------------- classifier stage 2: out = h1 @ Wc2 + bc2 ----------------

__global__ __launch_bounds__(256) void cls2_kernel(const float* __restrict__ h1,
    const float* __restrict__ Wc2, const float* __restrict__ bc2,
    float* __restrict__ out, int n) {
  __shared__ float W2[HID * NC];
  __shared__ float b2[NC];
  int tid = threadIdx.x;
  for (int i = tid; i < HID * NC; i += 256) W2[i] = Wc2[i];
  if (tid < NC) b2[tid] = bc2[tid];
  __syncthreads();
  int row = blockIdx.x * 256 + tid;
  if (row >= n) return;
  float a[NC];
#pragma unroll
  for (int mm = 0; mm < NC; mm++) a[mm] = b2[mm];
  const float4* hp = (const float4*)(h1 + (size_t)row * HID);
#pragma unroll
  for (int k4 = 0; k4 < 16; k4++) {
    float4 hv = hp[k4];
    float h_[4] = {hv.x, hv.y, hv.z, hv.w};
#pragma unroll
    for (int kk = 0; kk < 4; kk++)
#pragma unroll
      for (int mm = 0; mm < NC; mm++)
        a[mm] = fmaf(h_[kk], W2[(k4 * 4 + kk) * NC + mm], a[mm]);
  }
#pragma unroll
  for (int mm = 0; mm < NC; mm++) out[(size_t)row * NC + mm] = a[mm];
}

// ---------------- launch ----------------

extern "C" void kernel_launch(void* const* d_in, const int* in_sizes, int n_in,
                              void* d_out, int out_size, void* d_ws, size_t ws_size,
                              hipStream_t stream) {
  const float* x     = (const float*)d_in[0];
  const int*   eidx  = (const int*)d_in[1];
  const float* eattr = (const float*)d_in[2];
  const float* Win   = (const float*)d_in[3];
  const float* b_in  = (const float*)d_in[4];
  const float* Wq    = (const float*)d_in[5];
  const float* bq    = (const float*)d_in[6];
  const float* Wk    = (const float*)d_in[7];
  const float* bk    = (const float*)d_in[8];
  const float* Wv    = (const float*)d_in[9];
  const float* bv    = (const float*)d_in[10];
  const float* Wedge = (const float*)d_in[11];
  const float* Wskip = (const float*)d_in[12];
  const float* bskip = (const float*)d_in[13];
  const float* Wbeta = (const float*)d_in[14];
  const float* ln_g  = (const float*)d_in[15];
  const float* ln_b  = (const float*)d_in[16];
  const float* Wc1   = (const float*)d_in[17];
  const float* bc1   = (const float*)d_in[18];
  const float* Wc2   = (const float*)d_in[19];
  const float* bc2   = (const float*)d_in[20];
  float* out = (float*)d_out;

  int n = in_sizes[0] / IN_F;   // 50000
  int e = in_sizes[2];          // 800000
  const int* src = eidx;
  const int* dstp = eidx + e;

  char* ws = (char*)d_ws;
  size_t off = 0;
  auto alloc = [&](size_t bytes) { void* p = ws + off; off += (bytes + 255) & ~(size_t)255; return p; };
  int*    rowptr = (int*)alloc((size_t)(n + 1) * 4);
  int*    fill   = (int*)alloc((size_t)n * 4);
  int*    part   = (int*)alloc(64 * 4);
  unsigned long long* edges = (unsigned long long*)alloc((size_t)e * 8);
  float*  h      = (float*)alloc((size_t)n * HID * 4);
  float*  qkvx   = (float*)alloc((size_t)n * 256 * 4);
  __half* kvb    = (__half*)alloc((size_t)n * 128 * 2);
  float*  h1     = (float*)alloc((size_t)n * HID * 4);

  int nb = (n + 1023) / 1024;   // 49 (fits in one wave's scan)

  hipMemsetAsync(fill, 0, (size_t)n * 4, stream);
  count_kernel<<<(e + 255) / 256, 256, 0, stream>>>(dstp, fill, e);
  scan_reduce_kernel<<<nb, 256, 0, stream>>>(fill, part, n);
  scan_part_kernel<<<1, 64, 0, stream>>>(part, nb, rowptr + n);
  scan_apply_kernel<<<nb, 256, 0, stream>>>(fill, part, rowptr, n);
  scatter_kernel<<<(e + 255) / 256, 256, 0, stream>>>(src, dstp, eattr, rowptr, fill, edges, e);

  int mtiles = (n + 63) / 64;   // 782
  gemm_tiled<IN_F, 1, false, false><<<dim3(mtiles, 1), 256, 0, stream>>>(
      x, IN_F, n, Win, Win, Win, Win, b_in, b_in, b_in, b_in, h, HID, nullptr);

  for (int i = 0; i < 3; i++) {
    gemm_tiled<HID, 2, false, true><<<dim3(mtiles, 2), 256, 0, stream>>>(
        h, HID, n,
        Wq + i * HID * HID, Wk + i * HID * HID, Wv + i * HID * HID, Wskip + i * HID * HID,
        bq + i * HID, bk + i * HID, bv + i * HID, bskip + i * HID,
        qkvx, 256, kvb);
    attn_post_kernel<<<(n + 3) / 4, 256, 0, stream>>>(
        rowptr, edges, qkvx, (const uint4*)kvb, Wedge + i * HID, Wbeta + i * 3 * HID,
        ln_g + i * HID, ln_b + i * HID, h, n);
  }

  gemm_tiled<HID, 1, true, false><<<dim3(mtiles, 1), 256, 0, stream>>>(
      h, HID, n, Wc1, Wc1, Wc1, Wc1, bc1, bc1, bc1, bc1, h1, HID, nullptr);
  cls2_kernel<<<(n + 255) / 256, 256, 0, stream>>>(h1, Wc2, bc2, out, n);
}

// Round 6
// 494.950 us; speedup vs baseline: 1.0237x; 1.0237x over previous
//
#include <hip/hip_runtime.h>
#include <hip/hip_fp16.h>
#include <math.h>

#define IN_F 50
#define HID 64
#define NC 12
#define LN_EPS 1e-5f

// Bucketed CSR build parameters
#define BSH 8                 // bucket = dst >> 8 (256 nodes per bucket)
#define BSZ 256
#define CHUNK 8192            // edges per phase-B block
#define PCAP 8192             // LDS staging capacity per bucket (mean 4096, +64 sigma)

// ---------------- CSR construction ----------------

__global__ void count_kernel(const int* __restrict__ dst, int* __restrict__ cnt, int e) {
  int i = blockIdx.x * blockDim.x + threadIdx.x;
  if (i < e) atomicAdd(&cnt[dst[i]], 1);
}

// ---- 3-phase exclusive scan over n counts (chunk = 1024 per block) ----

__global__ __launch_bounds__(256) void scan_reduce_kernel(const int* __restrict__ cnt,
                                                          int* __restrict__ part, int n) {
  int base = blockIdx.x * 1024;
  int sum = 0;
  for (int i = threadIdx.x; i < 1024; i += 256) {
    int g = base + i;
    if (g < n) sum += cnt[g];
  }
#pragma unroll
  for (int off = 1; off < 64; off <<= 1) sum += __shfl_xor(sum, off);
  __shared__ int ws[4];
  if ((threadIdx.x & 63) == 0) ws[threadIdx.x >> 6] = sum;
  __syncthreads();
  if (threadIdx.x == 0) part[blockIdx.x] = ws[0] + ws[1] + ws[2] + ws[3];
}

__global__ void scan_part_kernel(int* __restrict__ part, int nb, int* __restrict__ total) {
  int lane = threadIdx.x;
  int orig = (lane < nb) ? part[lane] : 0;
  int v = orig;
#pragma unroll
  for (int off = 1; off < 64; off <<= 1) {
    int t = __shfl_up(v, off);
    if (lane >= off) v += t;
  }
  if (lane < nb) part[lane] = v - orig;   // exclusive
  if (lane == 63) *total = v;             // rowptr[n]
}

__global__ __launch_bounds__(256) void scan_apply_kernel(const int* __restrict__ cnt,
    const int* __restrict__ part, int* __restrict__ rowptr, int n) {
  int base = blockIdx.x * 1024;
  int t = threadIdx.x;
  int vals[4];
  int lsum = 0;
#pragma unroll
  for (int j = 0; j < 4; j++) {
    int g = base + t * 4 + j;
    vals[j] = (g < n) ? cnt[g] : 0;
    lsum += vals[j];
  }
  int v = lsum;
#pragma unroll
  for (int off = 1; off < 64; off <<= 1) {
    int tv = __shfl_up(v, off);
    if ((t & 63) >= off) v += tv;
  }
  __shared__ int wsum[4];
  if ((t & 63) == 63) wsum[t >> 6] = v;
  __syncthreads();
  int wbase = 0;
  int w = t >> 6;
#pragma unroll
  for (int j = 0; j < 4; j++) if (j < w) wbase += wsum[j];
  int excl = v - lsum + wbase + part[blockIdx.x];
#pragma unroll
  for (int j = 0; j < 4; j++) {
    int g = base + t * 4 + j;
    if (g < n) rowptr[g] = excl;
    excl += vals[j];
  }
}

__global__ void cursor_init_kernel(const int* __restrict__ rowptr,
                                   int* __restrict__ cursor, int n, int nbk) {
  int b = blockIdx.x * blockDim.x + threadIdx.x;
  if (b < nbk) cursor[b] = rowptr[min(b * BSZ, n)];
}

// Phase B: partition edges into dst-buckets. Each block's writes form dense
// private runs (~42 edges) inside its bucket region -> L2 write-combining works.
__global__ __launch_bounds__(256) void bucket_kernel(
    const int* __restrict__ src, const int* __restrict__ dst,
    const float* __restrict__ ea, int* __restrict__ cursor,
    unsigned long long* __restrict__ rec_stage,
    unsigned short* __restrict__ dloc_stage, int e)
{
  __shared__ int bcnt[256];
  __shared__ int gbase[256];
  __shared__ int bfill[256];
  int tid = threadIdx.x;
  bcnt[tid] = 0; bfill[tid] = 0;
  __syncthreads();
  int cb = blockIdx.x * CHUNK;
  int ce = min(cb + CHUNK, e);
  for (int i = cb + tid; i < ce; i += 256)
    atomicAdd(&bcnt[dst[i] >> BSH], 1);
  __syncthreads();
  if (bcnt[tid] > 0) gbase[tid] = atomicAdd(&cursor[tid], bcnt[tid]);
  __syncthreads();
  for (int i = cb + tid; i < ce; i += 256) {
    int d = dst[i];
    int b = d >> BSH;
    int slot = atomicAdd(&bfill[b], 1);
    int pos = gbase[b] + slot;
    rec_stage[pos] =
        ((unsigned long long)__float_as_uint(ea[i]) << 32) | (unsigned int)src[i];
    dloc_stage[pos] = (unsigned short)(d & (BSZ - 1));
  }
}

// Phase C: exact CSR placement within each bucket, staged in LDS, written
// out fully coalesced.
__global__ __launch_bounds__(256) void place_kernel(
    const int* __restrict__ rowptr,
    const unsigned long long* __restrict__ rec_stage,
    const unsigned short* __restrict__ dloc_stage,
    unsigned long long* __restrict__ edges, int n)
{
  extern __shared__ char smem[];
  unsigned long long* sbuf = (unsigned long long*)smem;       // PCAP * 8
  int* lrp  = (int*)(smem + (size_t)PCAP * 8);                // BSZ
  int* lcnt = lrp + BSZ;                                      // BSZ
  int lo = blockIdx.x * BSZ;
  int hi = min(lo + BSZ, n);
  int nb = hi - lo;
  int tid = threadIdx.x;
  if (tid < nb) { lrp[tid] = rowptr[lo + tid]; lcnt[tid] = 0; }
  __syncthreads();
  int base = rowptr[lo];
  int cnt  = rowptr[hi] - base;
  for (int i = tid; i < cnt; i += 256) {
    unsigned long long rec = rec_stage[base + i];
    int dl = dloc_stage[base + i];
    int slot = (lrp[dl] - base) + atomicAdd(&lcnt[dl], 1);
    if (slot < PCAP) sbuf[slot] = rec;
    else edges[(size_t)base + slot] = rec;   // overflow fallback (correct, never hit)
  }
  __syncthreads();
  int lim = min(cnt, PCAP);
  for (int i = tid; i < lim; i += 256)
    edges[(size_t)base + i] = sbuf[i];
}

// ---------------- generic tiled GEMM: C[M][*] = A[M][K] @ B[K][NCG*64] + bias ----------------
// WKV: cg==1 (k) / cg==2 (v) -> fp16 interleaved kvb; cg==0 (q) / cg==3 (xr)
// -> compact qx buffer [node][128] (cols 0-63 = q, 64-127 = xr).

template<int K, int NCG, bool RELU, bool WKV>
__global__ __launch_bounds__(256, 3) void gemm_tiled(
    const float* __restrict__ A, int lda, int M,
    const float* __restrict__ B0, const float* __restrict__ B1,
    const float* __restrict__ B2, const float* __restrict__ B3,
    const float* __restrict__ g0, const float* __restrict__ g1,
    const float* __restrict__ g2, const float* __restrict__ g3,
    float* __restrict__ C, int ldc, __half* __restrict__ kvb)
{
  constexpr int NT = NCG * 64;
  __shared__ __align__(16) float Ash[K * 68];   // A^T: Ash[k*68 + row]
  __shared__ __align__(16) float Bsh[K * NT];
  __shared__ float bsh[NT];
  const int tid = threadIdx.x;
  const int row0 = blockIdx.x * 64;
  for (int i = tid; i < 64 * K; i += 256) {
    int r = i / K, k = i - r * K;
    int gr = row0 + r;
    Ash[k * 68 + r] = (gr < M) ? A[gr * lda + k] : 0.f;
  }
#pragma unroll
  for (int g = 0; g < NCG; g++) {
    int cg = blockIdx.y * NCG + g;
    const float* Bp = (cg == 0) ? B0 : (cg == 1) ? B1 : (cg == 2) ? B2 : B3;
    const float* bp = (cg == 0) ? g0 : (cg == 1) ? g1 : (cg == 2) ? g2 : g3;
    for (int i = tid; i < 64 * K; i += 256) {
      int k = i >> 6, c = i & 63;
      Bsh[k * NT + g * 64 + c] = Bp[k * 64 + c];
    }
    if (tid < 64) bsh[g * 64 + tid] = bp[tid];
  }
  __syncthreads();
  const int ty = tid >> 4, tx = tid & 15;
  float acc[4][NCG * 4];
#pragma unroll
  for (int i = 0; i < 4; i++)
#pragma unroll
    for (int g = 0; g < NCG; g++)
#pragma unroll
      for (int c = 0; c < 4; c++)
        acc[i][g * 4 + c] = bsh[g * 64 + tx * 4 + c];
#pragma unroll 4
  for (int k = 0; k < K; k++) {
    float4 av = *(const float4*)&Ash[k * 68 + ty * 4];
    float a_[4] = {av.x, av.y, av.z, av.w};
    float b_[NCG][4];
#pragma unroll
    for (int g = 0; g < NCG; g++) {
      float4 bv = *(const float4*)&Bsh[k * NT + g * 64 + tx * 4];
      b_[g][0] = bv.x; b_[g][1] = bv.y; b_[g][2] = bv.z; b_[g][3] = bv.w;
    }
#pragma unroll
    for (int i = 0; i < 4; i++)
#pragma unroll
      for (int g = 0; g < NCG; g++)
#pragma unroll
        for (int c = 0; c < 4; c++)
          acc[i][g * 4 + c] = fmaf(a_[i], b_[g][c], acc[i][g * 4 + c]);
  }
#pragma unroll
  for (int i = 0; i < 4; i++) {
    int r = row0 + ty * 4 + i;
    if (r < M) {
#pragma unroll
      for (int g = 0; g < NCG; g++) {
        int cg = blockIdx.y * NCG + g;
        if (WKV && (cg == 1 || cg == 2)) {
          __half hv[4];
#pragma unroll
          for (int c = 0; c < 4; c++) hv[c] = __float2half(acc[i][g * 4 + c]);
          *(ushort4*)&kvb[(size_t)r * 128 + tx * 8 + ((cg == 1) ? 0 : 4)] =
              *(ushort4*)hv;
        } else {
          int cbase = WKV ? ((cg == 0) ? 0 : 64) : cg * 64;
          float4 ov;
          ov.x = acc[i][g * 4 + 0]; ov.y = acc[i][g * 4 + 1];
          ov.z = acc[i][g * 4 + 2]; ov.w = acc[i][g * 4 + 3];
          if (RELU) {
            ov.x = fmaxf(ov.x, 0.f); ov.y = fmaxf(ov.y, 0.f);
            ov.z = fmaxf(ov.z, 0.f); ov.w = fmaxf(ov.w, 0.f);
          }
          *(float4*)&C[(size_t)r * ldc + cbase + tx * 4] = ov;
        }
      }
    }
  }
}

// ---------------- fused attention + gate + LayerNorm ----------------
// qx layout:  [node][128] = q(0:64) | xr(64:128)
// kvb layout: [node][16 uint4]: lane c4 -> {k[c4*4..+3], v[c4*4..+3]} fp16
// edges: 8B packed (ea<<32 | src)

__global__ __launch_bounds__(256) void attn_post_kernel(
    const int* __restrict__ rowptr, const unsigned long long* __restrict__ edges,
    const float* __restrict__ qx, const uint4* __restrict__ kvb,
    const float* __restrict__ wedge, const float* __restrict__ wbeta,
    const float* __restrict__ lng, const float* __restrict__ lnb,
    float* __restrict__ h, int n)
{
  int lane = threadIdx.x & 63;
  int node = blockIdx.x * 4 + (threadIdx.x >> 6);
  if (node >= n) return;
  int grp = lane >> 4;
  int c4 = lane & 15;
  const float4* row4 = (const float4*)qx;   // 32 float4 per node row
  float4 q4 = row4[(size_t)node * 32 + c4];
  float4 we4 = ((const float4*)wedge)[c4];
  int s0 = rowptr[node], s1 = rowptr[node + 1];
  float m = -INFINITY, l = 0.f;
  float ax = 0.f, ay = 0.f, az = 0.f, aw = 0.f;
  for (int s = s0; s < s1; s += 4) {
    int es = s + grp;
    bool valid = es < s1;
    unsigned long long rec = valid ? edges[es] : 0ull;
    int srcn = (int)(unsigned int)(rec & 0xffffffffu);
    float a = __uint_as_float((unsigned int)(rec >> 32));
    float ex = a * we4.x, ey = a * we4.y, ez = a * we4.z, ew = a * we4.w;
    uint4 kv = kvb[(size_t)srcn * 16 + c4];          // one dwordx4 per edge
    float2 k01 = __half22float2(*(__half2*)&kv.x);
    float2 k23 = __half22float2(*(__half2*)&kv.y);
    float2 v01 = __half22float2(*(__half2*)&kv.z);
    float2 v23 = __half22float2(*(__half2*)&kv.w);
    float prod = q4.x * (k01.x + ex) + q4.y * (k01.y + ey)
               + q4.z * (k23.x + ez) + q4.w * (k23.y + ew);
    prod += __shfl_xor(prod, 1);
    prod += __shfl_xor(prod, 2);            // per-head 16-chan dot
    float alpha = valid ? prod * 0.25f : -INFINITY;
    float am = alpha;
    am = fmaxf(am, __shfl_xor(am, 16));
    am = fmaxf(am, __shfl_xor(am, 32));     // max over 4 edge slots
    float mnew = fmaxf(m, am);
    float msafe = (mnew == -INFINITY) ? 0.f : mnew;
    float scale = __expf(m - msafe);
    float p = __expf(alpha - msafe);
    float ps = p;
    ps += __shfl_xor(ps, 16);
    ps += __shfl_xor(ps, 32);
    l = l * scale + ps;
    ax = ax * scale + p * (v01.x + ex);
    ay = ay * scale + p * (v01.y + ey);
    az = az * scale + p * (v23.x + ez);
    aw = aw * scale + p * (v23.y + ew);
    m = mnew;
  }
  ax += __shfl_xor(ax, 16); ax += __shfl_xor(ax, 32);
  ay += __shfl_xor(ay, 16); ay += __shfl_xor(ay, 32);
  az += __shfl_xor(az, 16); az += __shfl_xor(az, 32);
  aw += __shfl_xor(aw, 16); aw += __shfl_xor(aw, 32);
  float inv = 1.f / (l + 1e-16f);
  float ox = ax * inv, oy = ay * inv, oz = az * inv, ow = aw * inv;
  float4 xr = row4[(size_t)node * 32 + 16 + c4];
  float4 hr = ((const float4*)h)[(size_t)node * 16 + c4];
  float4 w1 = ((const float4*)wbeta)[c4];
  float4 w2 = ((const float4*)wbeta)[16 + c4];
  float4 w3 = ((const float4*)wbeta)[32 + c4];
  float sv = ox * w1.x + oy * w1.y + oz * w1.z + ow * w1.w
           + xr.x * w2.x + xr.y * w2.y + xr.z * w2.z + xr.w * w2.w
           + (ox - xr.x) * w3.x + (oy - xr.y) * w3.y
           + (oz - xr.z) * w3.z + (ow - xr.w) * w3.w;
  sv += __shfl_xor(sv, 1); sv += __shfl_xor(sv, 2);
  sv += __shfl_xor(sv, 4); sv += __shfl_xor(sv, 8);
  float beta = 1.f / (1.f + __expf(-sv));
  float zx = beta * xr.x + (1.f - beta) * ox + hr.x;
  float zy = beta * xr.y + (1.f - beta) * oy + hr.y;
  float zz = beta * xr.z + (1.f - beta) * oz + hr.z;
  float zw = beta * xr.w + (1.f - beta) * ow + hr.w;
  float mu = zx + zy + zz + zw;
  mu += __shfl_xor(mu, 1); mu += __shfl_xor(mu, 2);
  mu += __shfl_xor(mu, 4); mu += __shfl_xor(mu, 8);
  mu *= (1.f / 64.f);
  float dx = zx - mu, dy = zy - mu, dz = zz - mu, dw = zw - mu;
  float var = dx * dx + dy * dy + dz * dz + dw * dw;
  var += __shfl_xor(var, 1); var += __shfl_xor(var, 2);
  var += __shfl_xor(var, 4); var += __shfl_xor(var, 8);
  var *= (1.f / 64.f);
  float rstd = rsqrtf(var + LN_EPS);
  float4 g4 = ((const float4*)lng)[c4];
  float4 b4 = ((const float4*)lnb)[c4];
  if (grp == 0) {
    float4 res;
    res.x = dx * rstd * g4.x + b4.x;
    res.y = dy * rstd * g4.y + b4.y;
    res.z = dz * rstd * g4.z + b4.z;
    res.w = dw * rstd * g4.w + b4.w;
    ((float4*)h)[(size_t)node * 16 + c4] = res;
  }
}

// ---------------- classifier stage 2: out = h1 @ Wc2 + bc2 ----------------

__global__ __launch_bounds__(256) void cls2_kernel(const float* __restrict__ h1,
    const float* __restrict__ Wc2, const float* __restrict__ bc2,
    float* __restrict__ out, int n) {
  __shared__ float W2[HID * NC];
  __shared__ float b2[NC];
  int tid = threadIdx.x;
  for (int i = tid; i < HID * NC; i += 256) W2[i] = Wc2[i];
  if (tid < NC) b2[tid] = bc2[tid];
  __syncthreads();
  int row = blockIdx.x * 256 + tid;
  if (row >= n) return;
  float a[NC];
#pragma unroll
  for (int mm = 0; mm < NC; mm++) a[mm] = b2[mm];
  const float4* hp = (const float4*)(h1 + (size_t)row * HID);
#pragma unroll
  for (int k4 = 0; k4 < 16; k4++) {
    float4 hv = hp[k4];
    float h_[4] = {hv.x, hv.y, hv.z, hv.w};
#pragma unroll
    for (int kk = 0; kk < 4; kk++)
#pragma unroll
      for (int mm = 0; mm < NC; mm++)
        a[mm] = fmaf(h_[kk], W2[(k4 * 4 + kk) * NC + mm], a[mm]);
  }
#pragma unroll
  for (int mm = 0; mm < NC; mm++) out[(size_t)row * NC + mm] = a[mm];
}

// ---------------- launch ----------------

extern "C" void kernel_launch(void* const* d_in, const int* in_sizes, int n_in,
                              void* d_out, int out_size, void* d_ws, size_t ws_size,
                              hipStream_t stream) {
  const float* x     = (const float*)d_in[0];
  const int*   eidx  = (const int*)d_in[1];
  const float* eattr = (const float*)d_in[2];
  const float* Win   = (const float*)d_in[3];
  const float* b_in  = (const float*)d_in[4];
  const float* Wq    = (const float*)d_in[5];
  const float* bq    = (const float*)d_in[6];
  const float* Wk    = (const float*)d_in[7];
  const float* bk    = (const float*)d_in[8];
  const float* Wv    = (const float*)d_in[9];
  const float* bv    = (const float*)d_in[10];
  const float* Wedge = (const float*)d_in[11];
  const float* Wskip = (const float*)d_in[12];
  const float* bskip = (const float*)d_in[13];
  const float* Wbeta = (const float*)d_in[14];
  const float* ln_g  = (const float*)d_in[15];
  const float* ln_b  = (const float*)d_in[16];
  const float* Wc1   = (const float*)d_in[17];
  const float* bc1   = (const float*)d_in[18];
  const float* Wc2   = (const float*)d_in[19];
  const float* bc2   = (const float*)d_in[20];
  float* out = (float*)d_out;

  int n = in_sizes[0] / IN_F;   // 50000
  int e = in_sizes[2];          // 800000
  const int* src = eidx;
  const int* dstp = eidx + e;

  char* ws = (char*)d_ws;
  size_t off = 0;
  auto alloc = [&](size_t bytes) { void* p = ws + off; off += (bytes + 255) & ~(size_t)255; return p; };
  int*    rowptr = (int*)alloc((size_t)(n + 1) * 4);
  int*    fill   = (int*)alloc((size_t)n * 4);
  int*    part   = (int*)alloc(64 * 4);
  int*    cursor = (int*)alloc(256 * 4);
  unsigned long long* rec_stage = (unsigned long long*)alloc((size_t)e * 8);
  unsigned short*     dloc_stage = (unsigned short*)alloc((size_t)e * 2);
  unsigned long long* edges = (unsigned long long*)alloc((size_t)e * 8);
  float*  h      = (float*)alloc((size_t)n * HID * 4);
  float*  qx     = (float*)alloc((size_t)n * 128 * 4);
  __half* kvb    = (__half*)alloc((size_t)n * 128 * 2);
  float*  h1     = (float*)alloc((size_t)n * HID * 4);

  int nb  = (n + 1023) / 1024;        // 49 scan chunks
  int nbk = (n + BSZ - 1) / BSZ;      // 196 buckets

  hipMemsetAsync(fill, 0, (size_t)n * 4, stream);
  count_kernel<<<(e + 255) / 256, 256, 0, stream>>>(dstp, fill, e);
  scan_reduce_kernel<<<nb, 256, 0, stream>>>(fill, part, n);
  scan_part_kernel<<<1, 64, 0, stream>>>(part, nb, rowptr + n);
  scan_apply_kernel<<<nb, 256, 0, stream>>>(fill, part, rowptr, n);
  cursor_init_kernel<<<1, 256, 0, stream>>>(rowptr, cursor, n, nbk);
  bucket_kernel<<<(e + CHUNK - 1) / CHUNK, 256, 0, stream>>>(
      src, dstp, eattr, cursor, rec_stage, dloc_stage, e);
  size_t psmem = (size_t)PCAP * 8 + BSZ * 8;
  place_kernel<<<nbk, 256, psmem, stream>>>(rowptr, rec_stage, dloc_stage, edges, n);

  int mtiles = (n + 63) / 64;   // 782
  gemm_tiled<IN_F, 1, false, false><<<dim3(mtiles, 1), 256, 0, stream>>>(
      x, IN_F, n, Win, Win, Win, Win, b_in, b_in, b_in, b_in, h, HID, nullptr);

  for (int i = 0; i < 3; i++) {
    gemm_tiled<HID, 2, false, true><<<dim3(mtiles, 2), 256, 0, stream>>>(
        h, HID, n,
        Wq + i * HID * HID, Wk + i * HID * HID, Wv + i * HID * HID, Wskip + i * HID * HID,
        bq + i * HID, bk + i * HID, bv + i * HID, bskip + i * HID,
        qx, 128, kvb);
    attn_post_kernel<<<(n + 3) / 4, 256, 0, stream>>>(
        rowptr, edges, qx, (const uint4*)kvb, Wedge + i * HID, Wbeta + i * 3 * HID,
        ln_g + i * HID, ln_b + i * HID, h, n);
  }

  gemm_tiled<HID, 1, true, false><<<dim3(mtiles, 1), 256, 0, stream>>>(
      h, HID, n, Wc1, Wc1, Wc1, Wc1, bc1, bc1, bc1, bc1, h1, HID, nullptr);
  cls2_kernel<<<(n + 255) / 256, 256, 0, stream>>>(h1, Wc2, bc2, out, n);
}

// Round 8
// 458.499 us; speedup vs baseline: 1.1051x; 1.0795x over previous
//
#include <hip/hip_runtime.h>
#include <hip/hip_fp16.h>
#include <math.h>

#define IN_F 50
#define HID 64
#define NC 12
#define LN_EPS 1e-5f

// Bucketed CSR build parameters
#define BSH 8                 // bucket = dst >> 8 (256 nodes per bucket)
#define BSZ 256
#define CHUNK 8192            // edges per phase-B block
#define PCAP 8192             // LDS staging capacity per bucket (mean 4096, +64 sigma)

// ---------------- CSR construction ----------------

__global__ void count_kernel(const int* __restrict__ dst, int* __restrict__ cnt, int e) {
  int i = blockIdx.x * blockDim.x + threadIdx.x;
  if (i < e) atomicAdd(&cnt[dst[i]], 1);
}

// ---- 3-phase exclusive scan over n counts (chunk = 1024 per block) ----

__global__ __launch_bounds__(256) void scan_reduce_kernel(const int* __restrict__ cnt,
                                                          int* __restrict__ part, int n) {
  int base = blockIdx.x * 1024;
  int sum = 0;
  for (int i = threadIdx.x; i < 1024; i += 256) {
    int g = base + i;
    if (g < n) sum += cnt[g];
  }
#pragma unroll
  for (int off = 1; off < 64; off <<= 1) sum += __shfl_xor(sum, off);
  __shared__ int ws[4];
  if ((threadIdx.x & 63) == 0) ws[threadIdx.x >> 6] = sum;
  __syncthreads();
  if (threadIdx.x == 0) part[blockIdx.x] = ws[0] + ws[1] + ws[2] + ws[3];
}

__global__ void scan_part_kernel(int* __restrict__ part, int nb, int* __restrict__ total) {
  int lane = threadIdx.x;
  int orig = (lane < nb) ? part[lane] : 0;
  int v = orig;
#pragma unroll
  for (int off = 1; off < 64; off <<= 1) {
    int t = __shfl_up(v, off);
    if (lane >= off) v += t;
  }
  if (lane < nb) part[lane] = v - orig;   // exclusive
  if (lane == 63) *total = v;             // rowptr[n]
}

__global__ __launch_bounds__(256) void scan_apply_kernel(const int* __restrict__ cnt,
    const int* __restrict__ part, int* __restrict__ rowptr, int n) {
  int base = blockIdx.x * 1024;
  int t = threadIdx.x;
  int vals[4];
  int lsum = 0;
#pragma unroll
  for (int j = 0; j < 4; j++) {
    int g = base + t * 4 + j;
    vals[j] = (g < n) ? cnt[g] : 0;
    lsum += vals[j];
  }
  int v = lsum;
#pragma unroll
  for (int off = 1; off < 64; off <<= 1) {
    int tv = __shfl_up(v, off);
    if ((t & 63) >= off) v += tv;
  }
  __shared__ int wsum[4];
  if ((t & 63) == 63) wsum[t >> 6] = v;
  __syncthreads();
  int wbase = 0;
  int w = t >> 6;
#pragma unroll
  for (int j = 0; j < 4; j++) if (j < w) wbase += wsum[j];
  int excl = v - lsum + wbase + part[blockIdx.x];
#pragma unroll
  for (int j = 0; j < 4; j++) {
    int g = base + t * 4 + j;
    if (g < n) rowptr[g] = excl;
    excl += vals[j];
  }
}

__global__ void cursor_init_kernel(const int* __restrict__ rowptr,
                                   int* __restrict__ cursor, int n, int nbk) {
  int b = blockIdx.x * blockDim.x + threadIdx.x;
  if (b < nbk) cursor[b] = rowptr[min(b * BSZ, n)];
}

// Phase B: partition edges into dst-buckets. Each block's writes form dense
// private runs inside its bucket region -> L2 write-combining works.
__global__ __launch_bounds__(256) void bucket_kernel(
    const int* __restrict__ src, const int* __restrict__ dst,
    const float* __restrict__ ea, int* __restrict__ cursor,
    unsigned long long* __restrict__ rec_stage,
    unsigned short* __restrict__ dloc_stage, int e)
{
  __shared__ int bcnt[256];
  __shared__ int gbase[256];
  __shared__ int bfill[256];
  int tid = threadIdx.x;
  bcnt[tid] = 0; bfill[tid] = 0;
  __syncthreads();
  int cb = blockIdx.x * CHUNK;
  int ce = min(cb + CHUNK, e);
  for (int i = cb + tid; i < ce; i += 256)
    atomicAdd(&bcnt[dst[i] >> BSH], 1);
  __syncthreads();
  if (bcnt[tid] > 0) gbase[tid] = atomicAdd(&cursor[tid], bcnt[tid]);
  __syncthreads();
  for (int i = cb + tid; i < ce; i += 256) {
    int d = dst[i];
    int b = d >> BSH;
    int slot = atomicAdd(&bfill[b], 1);
    int pos = gbase[b] + slot;
    rec_stage[pos] =
        ((unsigned long long)__float_as_uint(ea[i]) << 32) | (unsigned int)src[i];
    dloc_stage[pos] = (unsigned short)(d & (BSZ - 1));
  }
}

// Phase C: exact CSR placement within each bucket, staged in LDS, written
// out fully coalesced.
__global__ __launch_bounds__(256) void place_kernel(
    const int* __restrict__ rowptr,
    const unsigned long long* __restrict__ rec_stage,
    const unsigned short* __restrict__ dloc_stage,
    unsigned long long* __restrict__ edges, int n)
{
  extern __shared__ char smem[];
  unsigned long long* sbuf = (unsigned long long*)smem;       // PCAP * 8
  int* lrp  = (int*)(smem + (size_t)PCAP * 8);                // BSZ
  int* lcnt = lrp + BSZ;                                      // BSZ
  int lo = blockIdx.x * BSZ;
  int hi = min(lo + BSZ, n);
  int nb = hi - lo;
  int tid = threadIdx.x;
  if (tid < nb) { lrp[tid] = rowptr[lo + tid]; lcnt[tid] = 0; }
  __syncthreads();
  int base = rowptr[lo];
  int cnt  = rowptr[hi] - base;
  for (int i = tid; i < cnt; i += 256) {
    unsigned long long rec = rec_stage[base + i];
    int dl = dloc_stage[base + i];
    int slot = (lrp[dl] - base) + atomicAdd(&lcnt[dl], 1);
    if (slot < PCAP) sbuf[slot] = rec;
    else edges[(size_t)base + slot] = rec;   // overflow fallback (correct, never hit)
  }
  __syncthreads();
  int lim = min(cnt, PCAP);
  for (int i = tid; i < lim; i += 256)
    edges[(size_t)base + i] = sbuf[i];
}

// ---------------- generic tiled GEMM: C[M][*] = A[M][K] @ B[K][NCG*64] + bias ----------------
// WKV: cg==1 (k) / cg==2 (v) -> fp16 interleaved kvb; cg==0 (q) / cg==3 (xr)
// -> compact qx buffer [node][128] (cols 0-63 = q, 64-127 = xr).

template<int K, int NCG, bool RELU, bool WKV>
__global__ __launch_bounds__(256, 3) void gemm_tiled(
    const float* __restrict__ A, int lda, int M,
    const float* __restrict__ B0, const float* __restrict__ B1,
    const float* __restrict__ B2, const float* __restrict__ B3,
    const float* __restrict__ g0, const float* __restrict__ g1,
    const float* __restrict__ g2, const float* __restrict__ g3,
    float* __restrict__ C, int ldc, __half* __restrict__ kvb)
{
  constexpr int NT = NCG * 64;
  __shared__ __align__(16) float Ash[K * 68];   // A^T: Ash[k*68 + row]
  __shared__ __align__(16) float Bsh[K * NT];
  __shared__ float bsh[NT];
  const int tid = threadIdx.x;
  const int row0 = blockIdx.x * 64;
  for (int i = tid; i < 64 * K; i += 256) {
    int r = i / K, k = i - r * K;
    int gr = row0 + r;
    Ash[k * 68 + r] = (gr < M) ? A[gr * lda + k] : 0.f;
  }
#pragma unroll
  for (int g = 0; g < NCG; g++) {
    int cg = blockIdx.y * NCG + g;
    const float* Bp = (cg == 0) ? B0 : (cg == 1) ? B1 : (cg == 2) ? B2 : B3;
    const float* bp = (cg == 0) ? g0 : (cg == 1) ? g1 : (cg == 2) ? g2 : g3;
    for (int i = tid; i < 64 * K; i += 256) {
      int k = i >> 6, c = i & 63;
      Bsh[k * NT + g * 64 + c] = Bp[k * 64 + c];
    }
    if (tid < 64) bsh[g * 64 + tid] = bp[tid];
  }
  __syncthreads();
  const int ty = tid >> 4, tx = tid & 15;
  float acc[4][NCG * 4];
#pragma unroll
  for (int i = 0; i < 4; i++)
#pragma unroll
    for (int g = 0; g < NCG; g++)
#pragma unroll
      for (int c = 0; c < 4; c++)
        acc[i][g * 4 + c] = bsh[g * 64 + tx * 4 + c];
#pragma unroll 4
  for (int k = 0; k < K; k++) {
    float4 av = *(const float4*)&Ash[k * 68 + ty * 4];
    float a_[4] = {av.x, av.y, av.z, av.w};
    float b_[NCG][4];
#pragma unroll
    for (int g = 0; g < NCG; g++) {
      float4 bv = *(const float4*)&Bsh[k * NT + g * 64 + tx * 4];
      b_[g][0] = bv.x; b_[g][1] = bv.y; b_[g][2] = bv.z; b_[g][3] = bv.w;
    }
#pragma unroll
    for (int i = 0; i < 4; i++)
#pragma unroll
      for (int g = 0; g < NCG; g++)
#pragma unroll
        for (int c = 0; c < 4; c++)
          acc[i][g * 4 + c] = fmaf(a_[i], b_[g][c], acc[i][g * 4 + c]);
  }
#pragma unroll
  for (int i = 0; i < 4; i++) {
    int r = row0 + ty * 4 + i;
    if (r < M) {
#pragma unroll
      for (int g = 0; g < NCG; g++) {
        int cg = blockIdx.y * NCG + g;
        if (WKV && (cg == 1 || cg == 2)) {
          __half hv[4];
#pragma unroll
          for (int c = 0; c < 4; c++) hv[c] = __float2half(acc[i][g * 4 + c]);
          *(ushort4*)&kvb[(size_t)r * 128 + tx * 8 + ((cg == 1) ? 0 : 4)] =
              *(ushort4*)hv;
        } else {
          int cbase = WKV ? ((cg == 0) ? 0 : 64) : cg * 64;
          float4 ov;
          ov.x = acc[i][g * 4 + 0]; ov.y = acc[i][g * 4 + 1];
          ov.z = acc[i][g * 4 + 2]; ov.w = acc[i][g * 4 + 3];
          if (RELU) {
            ov.x = fmaxf(ov.x, 0.f); ov.y = fmaxf(ov.y, 0.f);
            ov.z = fmaxf(ov.z, 0.f); ov.w = fmaxf(ov.w, 0.f);
          }
          *(float4*)&C[(size_t)r * ldc + cbase + tx * 4] = ov;
        }
      }
    }
  }
}

// ---------------- fused attention + gate + LayerNorm ----------------
// qx layout:  [node][128] = q(0:64) | xr(64:128)
// kvb layout: [node][16 uint4]: lane c4 -> {k[c4*4..+3], v[c4*4..+3]} fp16
// edges: 8B packed (ea<<32 | src)
//
// Math: softmax is shift-invariant; alpha=(q.(k+a*we))/4 is bounded (LN-normed h),
// so no running-max needed. Factorizations:
//   q.(k+a*we)   = q.k + a*(q.we)       -> per-lane qwe precomputed
//   sum p*(v+a*we)= sum p*v + (sum p*a)*we -> scalar pa accumulator
// log2e*0.25 folded into qs/qwe -> exp2f directly. Cross-group (xor16/32)
// reductions deferred to the epilogue.

__global__ __launch_bounds__(256) void attn_post_kernel(
    const int* __restrict__ rowptr, const unsigned long long* __restrict__ edges,
    const float* __restrict__ qx, const uint4* __restrict__ kvb,
    const float* __restrict__ wedge, const float* __restrict__ wbeta,
    const float* __restrict__ lng, const float* __restrict__ lnb,
    float* __restrict__ h, int n)
{
  int lane = threadIdx.x & 63;
  int node = blockIdx.x * 4 + (threadIdx.x >> 6);
  if (node >= n) return;
  int grp = lane >> 4;
  int c4 = lane & 15;
  const float4* row4 = (const float4*)qx;   // 32 float4 per node row
  float4 q4 = row4[(size_t)node * 32 + c4];
  float4 we4 = ((const float4*)wedge)[c4];
  const float SC = 0.25f * 1.44269504f;     // 1/sqrt(C) * log2(e)
  float4 qs;
  qs.x = q4.x * SC; qs.y = q4.y * SC; qs.z = q4.z * SC; qs.w = q4.w * SC;
  float qwe = qs.x * we4.x + qs.y * we4.y + qs.z * we4.z + qs.w * we4.w;
  int s0 = rowptr[node], s1 = rowptr[node + 1];
  float l = 0.f, pa = 0.f;
  float ax = 0.f, ay = 0.f, az = 0.f, aw = 0.f;
  for (int cb = s0; cb < s1; cb += 64) {
    int cnt = min(64, s1 - cb);
    // batched coalesced edge load: one record per lane
    unsigned long long rec64 = (lane < cnt) ? edges[cb + lane] : 0ull;
    unsigned int my_src = (unsigned int)(rec64 & 0xffffffffu);
    unsigned int my_ea  = (unsigned int)(rec64 >> 32);
    for (int j = 0; j * 4 < cnt; j++) {
      int sl = j * 4 + grp;
      bool valid = sl < cnt;
      int srcn   = (int)__shfl(my_src, sl);
      float a    = __uint_as_float(__shfl(my_ea, sl));
      uint4 kv = kvb[(size_t)srcn * 16 + c4];          // one dwordx4 per edge
      float2 k01 = __half22float2(*(__half2*)&kv.x);
      float2 k23 = __half22float2(*(__half2*)&kv.y);
      float2 v01 = __half22float2(*(__half2*)&kv.z);
      float2 v23 = __half22float2(*(__half2*)&kv.w);
      float prod = qs.x * k01.x + qs.y * k01.y + qs.z * k23.x + qs.w * k23.y
                 + a * qwe;
      prod += __shfl_xor(prod, 1);
      prod += __shfl_xor(prod, 2);            // per-head 16-chan dot (in log2 units)
      float p = valid ? exp2f(prod) : 0.f;
      l  += p;
      pa += p * a;
      ax += p * v01.x;
      ay += p * v01.y;
      az += p * v23.x;
      aw += p * v23.y;
    }
  }
  // fold in the edge-feature term, then reduce across the 4 edge-slot groups
  ax += pa * we4.x; ay += pa * we4.y; az += pa * we4.z; aw += pa * we4.w;
  ax += __shfl_xor(ax, 16); ax += __shfl_xor(ax, 32);
  ay += __shfl_xor(ay, 16); ay += __shfl_xor(ay, 32);
  az += __shfl_xor(az, 16); az += __shfl_xor(az, 32);
  aw += __shfl_xor(aw, 16); aw += __shfl_xor(aw, 32);
  l  += __shfl_xor(l, 16);  l  += __shfl_xor(l, 32);
  float inv = 1.f / (l + 1e-16f);
  float ox = ax * inv, oy = ay * inv, oz = az * inv, ow = aw * inv;
  float4 xr = row4[(size_t)node * 32 + 16 + c4];
  float4 hr = ((const float4*)h)[(size_t)node * 16 + c4];
  float4 w1 = ((const float4*)wbeta)[c4];
  float4 w2 = ((const float4*)wbeta)[16 + c4];
  float4 w3 = ((const float4*)wbeta)[32 + c4];
  float sv = ox * w1.x + oy * w1.y + oz * w1.z + ow * w1.w
           + xr.x * w2.x + xr.y * w2.y + xr.z * w2.z + xr.w * w2.w
           + (ox - xr.x) * w3.x + (oy - xr.y) * w3.y
           + (oz - xr.z) * w3.z + (ow - xr.w) * w3.w;
  sv += __shfl_xor(sv, 1); sv += __shfl_xor(sv, 2);
  sv += __shfl_xor(sv, 4); sv += __shfl_xor(sv, 8);
  float beta = 1.f / (1.f + __expf(-sv));
  float zx = beta * xr.x + (1.f - beta) * ox + hr.x;
  float zy = beta * xr.y + (1.f - beta) * oy + hr.y;
  float zz = beta * xr.z + (1.f - beta) * oz + hr.z;
  float zw = beta * xr.w + (1.f - beta) * ow + hr.w;
  float mu = zx + zy + zz + zw;
  mu += __shfl_xor(mu, 1); mu += __shfl_xor(mu, 2);
  mu += __shfl_xor(mu, 4); mu += __shfl_xor(mu, 8);
  mu *= (1.f / 64.f);
  float dx = zx - mu, dy = zy - mu, dz = zz - mu, dw = zw - mu;
  float var = dx * dx + dy * dy + dz * dz + dw * dw;
  var += __shfl_xor(var, 1); var += __shfl_xor(var, 2);
  var += __shfl_xor(var, 4); var += __shfl_xor(var, 8);
  var *= (1.f / 64.f);
  float rstd = rsqrtf(var + LN_EPS);
  float4 g4 = ((const float4*)lng)[c4];
  float4 b4 = ((const float4*)lnb)[c4];
  if (grp == 0) {
    float4 res;
    res.x = dx * rstd * g4.x + b4.x;
    res.y = dy * rstd * g4.y + b4.y;
    res.z = dz * rstd * g4.z + b4.z;
    res.w = dw * rstd * g4.w + b4.w;
    ((float4*)h)[(size_t)node * 16 + c4] = res;
  }
}

// ---------------- classifier stage 2: out = h1 @ Wc2 + bc2 ----------------

__global__ __launch_bounds__(256) void cls2_kernel(const float* __restrict__ h1,
    const float* __restrict__ Wc2, const float* __restrict__ bc2,
    float* __restrict__ out, int n) {
  __shared__ float W2[HID * NC];
  __shared__ float b2[NC];
  int tid = threadIdx.x;
  for (int i = tid; i < HID * NC; i += 256) W2[i] = Wc2[i];
  if (tid < NC) b2[tid] = bc2[tid];
  __syncthreads();
  int row = blockIdx.x * 256 + tid;
  if (row >= n) return;
  float a[NC];
#pragma unroll
  for (int mm = 0; mm < NC; mm++) a[mm] = b2[mm];
  const float4* hp = (const float4*)(h1 + (size_t)row * HID);
#pragma unroll
  for (int k4 = 0; k4 < 16; k4++) {
    float4 hv = hp[k4];
    float h_[4] = {hv.x, hv.y, hv.z, hv.w};
#pragma unroll
    for (int kk = 0; kk < 4; kk++)
#pragma unroll
      for (int mm = 0; mm < NC; mm++)
        a[mm] = fmaf(h_[kk], W2[(k4 * 4 + kk) * NC + mm], a[mm]);
  }
#pragma unroll
  for (int mm = 0; mm < NC; mm++) out[(size_t)row * NC + mm] = a[mm];
}

// ---------------- launch ----------------

extern "C" void kernel_launch(void* const* d_in, const int* in_sizes, int n_in,
                              void* d_out, int out_size, void* d_ws, size_t ws_size,
                              hipStream_t stream) {
  const float* x     = (const float*)d_in[0];
  const int*   eidx  = (const int*)d_in[1];
  const float* eattr = (const float*)d_in[2];
  const float* Win   = (const float*)d_in[3];
  const float* b_in  = (const float*)d_in[4];
  const float* Wq    = (const float*)d_in[5];
  const float* bq    = (const float*)d_in[6];
  const float* Wk    = (const float*)d_in[7];
  const float* bk    = (const float*)d_in[8];
  const float* Wv    = (const float*)d_in[9];
  const float* bv    = (const float*)d_in[10];
  const float* Wedge = (const float*)d_in[11];
  const float* Wskip = (const float*)d_in[12];
  const float* bskip = (const float*)d_in[13];
  const float* Wbeta = (const float*)d_in[14];
  const float* ln_g  = (const float*)d_in[15];
  const float* ln_b  = (const float*)d_in[16];
  const float* Wc1   = (const float*)d_in[17];
  const float* bc1   = (const float*)d_in[18];
  const float* Wc2   = (const float*)d_in[19];
  const float* bc2   = (const float*)d_in[20];
  float* out = (float*)d_out;

  int n = in_sizes[0] / IN_F;   // 50000
  int e = in_sizes[2];          // 800000
  const int* src = eidx;
  const int* dstp = eidx + e;

  char* ws = (char*)d_ws;
  size_t off = 0;
  auto alloc = [&](size_t bytes) { void* p = ws + off; off += (bytes + 255) & ~(size_t)255; return p; };
  int*    rowptr = (int*)alloc((size_t)(n + 1) * 4);
  int*    fill   = (int*)alloc((size_t)n * 4);
  int*    part   = (int*)alloc(64 * 4);
  int*    cursor = (int*)alloc(256 * 4);
  unsigned long long* rec_stage = (unsigned long long*)alloc((size_t)e * 8);
  unsigned short*     dloc_stage = (unsigned short*)alloc((size_t)e * 2);
  unsigned long long* edges = (unsigned long long*)alloc((size_t)e * 8);
  float*  h      = (float*)alloc((size_t)n * HID * 4);
  float*  qx     = (float*)alloc((size_t)n * 128 * 4);
  __half* kvb    = (__half*)alloc((size_t)n * 128 * 2);
  float*  h1     = (float*)alloc((size_t)n * HID * 4);

  int nb  = (n + 1023) / 1024;        // 49 scan chunks
  int nbk = (n + BSZ - 1) / BSZ;      // 196 buckets

  (void)hipMemsetAsync(fill, 0, (size_t)n * 4, stream);
  count_kernel<<<(e + 255) / 256, 256, 0, stream>>>(dstp, fill, e);
  scan_reduce_kernel<<<nb, 256, 0, stream>>>(fill, part, n);
  scan_part_kernel<<<1, 64, 0, stream>>>(part, nb, rowptr + n);
  scan_apply_kernel<<<nb, 256, 0, stream>>>(fill, part, rowptr, n);
  cursor_init_kernel<<<1, 256, 0, stream>>>(rowptr, cursor, n, nbk);
  bucket_kernel<<<(e + CHUNK - 1) / CHUNK, 256, 0, stream>>>(
      src, dstp, eattr, cursor, rec_stage, dloc_stage, e);
  size_t psmem = (size_t)PCAP * 8 + BSZ * 8;
  place_kernel<<<nbk, 256, psmem, stream>>>(rowptr, rec_stage, dloc_stage, edges, n);

  int mtiles = (n + 63) / 64;   // 782
  gemm_tiled<IN_F, 1, false, false><<<dim3(mtiles, 1), 256, 0, stream>>>(
      x, IN_F, n, Win, Win, Win, Win, b_in, b_in, b_in, b_in, h, HID, nullptr);

  for (int i = 0; i < 3; i++) {
    gemm_tiled<HID, 2, false, true><<<dim3(mtiles, 2), 256, 0, stream>>>(
        h, HID, n,
        Wq + i * HID * HID, Wk + i * HID * HID, Wv + i * HID * HID, Wskip + i * HID * HID,
        bq + i * HID, bk + i * HID, bv + i * HID, bskip + i * HID,
        qx, 128, kvb);
    attn_post_kernel<<<(n + 3) / 4, 256, 0, stream>>>(
        rowptr, edges, qx, (const uint4*)kvb, Wedge + i * HID, Wbeta + i * 3 * HID,
        ln_g + i * HID, ln_b + i * HID, h, n);
  }

  gemm_tiled<HID, 1, true, false><<<dim3(mtiles, 1), 256, 0, stream>>>(
      h, HID, n, Wc1, Wc1, Wc1, Wc1, bc1, bc1, bc1, bc1, h1, HID, nullptr);
  cls2_kernel<<<(n + 255) / 256, 256, 0, stream>>>(h1, Wc2, bc2, out, n);
}

// Round 9
// 380.029 us; speedup vs baseline: 1.3333x; 1.2065x over previous
//
#include <hip/hip_runtime.h>
#include <hip/hip_fp16.h>
#include <math.h>

#define IN_F 50
#define HID 64
#define NC 12
#define LN_EPS 1e-5f

// Bucketed CSR build parameters
#define BSH 8
#define BSZ 256
#define CHUNK 8192
#define PCAP 8192

typedef _Float16 half8 __attribute__((ext_vector_type(8)));
typedef _Float16 half4_t __attribute__((ext_vector_type(4)));
typedef float float4v __attribute__((ext_vector_type(4)));

// ---------------- CSR construction ----------------

__global__ void count_kernel(const int* __restrict__ dst, int* __restrict__ cnt, int e) {
  int i = blockIdx.x * blockDim.x + threadIdx.x;
  if (i < e) atomicAdd(&cnt[dst[i]], 1);
}

__global__ __launch_bounds__(256) void scan_reduce_kernel(const int* __restrict__ cnt,
                                                          int* __restrict__ part, int n) {
  int base = blockIdx.x * 1024;
  int sum = 0;
  for (int i = threadIdx.x; i < 1024; i += 256) {
    int g = base + i;
    if (g < n) sum += cnt[g];
  }
#pragma unroll
  for (int off = 1; off < 64; off <<= 1) sum += __shfl_xor(sum, off);
  __shared__ int ws[4];
  if ((threadIdx.x & 63) == 0) ws[threadIdx.x >> 6] = sum;
  __syncthreads();
  if (threadIdx.x == 0) part[blockIdx.x] = ws[0] + ws[1] + ws[2] + ws[3];
}

__global__ void scan_part_kernel(int* __restrict__ part, int nb, int* __restrict__ total) {
  int lane = threadIdx.x;
  int orig = (lane < nb) ? part[lane] : 0;
  int v = orig;
#pragma unroll
  for (int off = 1; off < 64; off <<= 1) {
    int t = __shfl_up(v, off);
    if (lane >= off) v += t;
  }
  if (lane < nb) part[lane] = v - orig;
  if (lane == 63) *total = v;
}

__global__ __launch_bounds__(256) void scan_apply_kernel(const int* __restrict__ cnt,
    const int* __restrict__ part, int* __restrict__ rowptr, int n) {
  int base = blockIdx.x * 1024;
  int t = threadIdx.x;
  int vals[4];
  int lsum = 0;
#pragma unroll
  for (int j = 0; j < 4; j++) {
    int g = base + t * 4 + j;
    vals[j] = (g < n) ? cnt[g] : 0;
    lsum += vals[j];
  }
  int v = lsum;
#pragma unroll
  for (int off = 1; off < 64; off <<= 1) {
    int tv = __shfl_up(v, off);
    if ((t & 63) >= off) v += tv;
  }
  __shared__ int wsum[4];
  if ((t & 63) == 63) wsum[t >> 6] = v;
  __syncthreads();
  int wbase = 0;
  int w = t >> 6;
#pragma unroll
  for (int j = 0; j < 4; j++) if (j < w) wbase += wsum[j];
  int excl = v - lsum + wbase + part[blockIdx.x];
#pragma unroll
  for (int j = 0; j < 4; j++) {
    int g = base + t * 4 + j;
    if (g < n) rowptr[g] = excl;
    excl += vals[j];
  }
}

__global__ void cursor_init_kernel(const int* __restrict__ rowptr,
                                   int* __restrict__ cursor, int n, int nbk) {
  int b = blockIdx.x * blockDim.x + threadIdx.x;
  if (b < nbk) cursor[b] = rowptr[min(b * BSZ, n)];
}

__global__ __launch_bounds__(256) void bucket_kernel(
    const int* __restrict__ src, const int* __restrict__ dst,
    const float* __restrict__ ea, int* __restrict__ cursor,
    unsigned long long* __restrict__ rec_stage,
    unsigned short* __restrict__ dloc_stage, int e)
{
  __shared__ int bcnt[256];
  __shared__ int gbase[256];
  __shared__ int bfill[256];
  int tid = threadIdx.x;
  bcnt[tid] = 0; bfill[tid] = 0;
  __syncthreads();
  int cb = blockIdx.x * CHUNK;
  int ce = min(cb + CHUNK, e);
  for (int i = cb + tid; i < ce; i += 256)
    atomicAdd(&bcnt[dst[i] >> BSH], 1);
  __syncthreads();
  if (bcnt[tid] > 0) gbase[tid] = atomicAdd(&cursor[tid], bcnt[tid]);
  __syncthreads();
  for (int i = cb + tid; i < ce; i += 256) {
    int d = dst[i];
    int b = d >> BSH;
    int slot = atomicAdd(&bfill[b], 1);
    int pos = gbase[b] + slot;
    rec_stage[pos] =
        ((unsigned long long)__float_as_uint(ea[i]) << 32) | (unsigned int)src[i];
    dloc_stage[pos] = (unsigned short)(d & (BSZ - 1));
  }
}

__global__ __launch_bounds__(256) void place_kernel(
    const int* __restrict__ rowptr,
    const unsigned long long* __restrict__ rec_stage,
    const unsigned short* __restrict__ dloc_stage,
    unsigned long long* __restrict__ edges, int n)
{
  extern __shared__ char smem[];
  unsigned long long* sbuf = (unsigned long long*)smem;
  int* lrp  = (int*)(smem + (size_t)PCAP * 8);
  int* lcnt = lrp + BSZ;
  int lo = blockIdx.x * BSZ;
  int hi = min(lo + BSZ, n);
  int nb = hi - lo;
  int tid = threadIdx.x;
  if (tid < nb) { lrp[tid] = rowptr[lo + tid]; lcnt[tid] = 0; }
  __syncthreads();
  int base = rowptr[lo];
  int cnt  = rowptr[hi] - base;
  for (int i = tid; i < cnt; i += 256) {
    unsigned long long rec = rec_stage[base + i];
    int dl = dloc_stage[base + i];
    int slot = (lrp[dl] - base) + atomicAdd(&lcnt[dl], 1);
    if (slot < PCAP) sbuf[slot] = rec;
    else edges[(size_t)base + slot] = rec;
  }
  __syncthreads();
  int lim = min(cnt, PCAP);
  for (int i = tid; i < lim; i += 256)
    edges[(size_t)base + i] = sbuf[i];
}

// ---------------- weight prep: fp16 transposed Wt[col][k] + packed bias ----------------
// col layout: 0..767 = layer l (256 each: q|k|v|skip x 64), 768..831 = Wc1, 832..895 = Win

__global__ __launch_bounds__(256) void wprep_kernel(
    const float* __restrict__ Wq, const float* __restrict__ Wk,
    const float* __restrict__ Wv, const float* __restrict__ Ws,
    const float* __restrict__ Wc1, const float* __restrict__ Win,
    const float* __restrict__ bq, const float* __restrict__ bk,
    const float* __restrict__ bv, const float* __restrict__ bs,
    const float* __restrict__ bc1, const float* __restrict__ bin,
    _Float16* __restrict__ Wt, float* __restrict__ biasP)
{
  int idx = blockIdx.x * 256 + threadIdx.x;
  if (idx >= 896 * 64) return;
  int col = idx >> 6, k = idx & 63;
  float w, b;
  if (col < 768) {
    int l = col >> 8, rem = col & 255;
    int mat = rem >> 6, c = rem & 63;
    const float* W  = (mat == 0) ? Wq : (mat == 1) ? Wk : (mat == 2) ? Wv : Ws;
    const float* bb = (mat == 0) ? bq : (mat == 1) ? bk : (mat == 2) ? bv : bs;
    w = W[((size_t)l * 64 + k) * 64 + c];
    b = bb[l * 64 + c];
  } else if (col < 832) {
    int c = col - 768;
    w = Wc1[k * 64 + c];
    b = bc1[c];
  } else {
    int c = col - 832;
    w = (k < IN_F) ? Win[k * 64 + c] : 0.f;
    b = bin[c];
  }
  Wt[idx] = (_Float16)w;
  if (k == 0) biasP[col] = b;
}

// ---------------- MFMA GEMM: C[M x NMAT*64] = A[M x K<=64] @ W + bias ----------------
// mfma_f32_16x16x32_f16. Block = 64 rows x 256 threads (4 waves).
// NMAT=4 MODE=1: wave m = matrix m (q,k,v,xr): q/xr -> qx fp32, k/v -> kvb fp16 interleaved.
// NMAT=1 MODE=0: wave w = rows [w*16, w*16+16), plain fp32 C (+RELU).
// Fragment layouts (verified, guide §3): A[m=lane&15][k=quad*8+j]; B[k][n=lane&15] same
// k-mapping; C/D col=lane&15, row=quad*4+reg.

template<int NMAT, int MODE, bool RELU>
__global__ __launch_bounds__(256) void gemm_mfma(
    const float* __restrict__ A, int lda, int kin, int M,
    const _Float16* __restrict__ Wt, const float* __restrict__ biasP,
    float* __restrict__ C, int ldc,
    float* __restrict__ qx, __half* __restrict__ kvb)
{
  __shared__ __align__(16) _Float16 hsh[64 * 72];          // A tile, stride 72 halves
  constexpr int KVSZ = (MODE == 1) ? 64 * 128 : 8;
  __shared__ __align__(16) __half kvsh[KVSZ];

  const int tid = threadIdx.x;
  const int wave = tid >> 6, lane = tid & 63;
  const int lrow = lane & 15, quad = lane >> 4;
  const int row0 = blockIdx.x * 64;
  constexpr int WPC = 4 / NMAT;          // waves per col-group
  const int cg = wave / WPC;
  const int wi = wave % WPC;

  // B-fragments: loaded once from global (L2-resident), 4 col-tiles x 2 k-steps
  half8 bf[4][2];
  const _Float16* wbase = Wt + (size_t)cg * 64 * 64;
#pragma unroll
  for (int ct = 0; ct < 4; ct++)
#pragma unroll
    for (int ks = 0; ks < 2; ks++)
      bf[ct][ks] = *(const half8*)&wbase[(ct * 16 + lrow) * 64 + ks * 32 + quad * 8];
  float bv_[4];
#pragma unroll
  for (int ct = 0; ct < 4; ct++) bv_[ct] = biasP[cg * 64 + ct * 16 + lrow];

  // stage A tile as fp16
  if (kin == 64) {
    int r = tid >> 2, cq = tid & 3;
    int grow = row0 + r;
#pragma unroll
    for (int i = 0; i < 4; i++) {
      int c0 = cq * 16 + i * 4;
      float4 v = make_float4(0.f, 0.f, 0.f, 0.f);
      if (grow < M) v = *(const float4*)&A[(size_t)grow * lda + c0];
      half4_t hv;
      hv[0] = (_Float16)v.x; hv[1] = (_Float16)v.y;
      hv[2] = (_Float16)v.z; hv[3] = (_Float16)v.w;
      *(half4_t*)&hsh[r * 72 + c0] = hv;
    }
  } else {
    for (int idx = tid; idx < 64 * 64; idx += 256) {
      int r = idx >> 6, c = idx & 63;
      int grow = row0 + r;
      float v = (grow < M && c < kin) ? A[(size_t)grow * lda + c] : 0.f;
      hsh[r * 72 + c] = (_Float16)v;
    }
  }
  __syncthreads();

  float4v acc[NMAT][4];
#pragma unroll
  for (int rt = 0; rt < NMAT; rt++)
#pragma unroll
    for (int ct = 0; ct < 4; ct++) {
      acc[rt][ct][0] = bv_[ct]; acc[rt][ct][1] = bv_[ct];
      acc[rt][ct][2] = bv_[ct]; acc[rt][ct][3] = bv_[ct];
    }

#pragma unroll
  for (int rt = 0; rt < NMAT; rt++) {
    int rbase = (wi * NMAT + rt) * 16;
#pragma unroll
    for (int ks = 0; ks < 2; ks++) {
      half8 af = *(const half8*)&hsh[(rbase + lrow) * 72 + ks * 32 + quad * 8];
#pragma unroll
      for (int ct = 0; ct < 4; ct++)
        acc[rt][ct] = __builtin_amdgcn_mfma_f32_16x16x32_f16(af, bf[ct][ks],
                                                             acc[rt][ct], 0, 0, 0);
    }
  }

  if (MODE == 0) {
#pragma unroll
    for (int rt = 0; rt < NMAT; rt++) {
      int rbase = (wi * NMAT + rt) * 16;
#pragma unroll
      for (int reg = 0; reg < 4; reg++) {
        int row = row0 + rbase + quad * 4 + reg;
        if (row < M) {
#pragma unroll
          for (int ct = 0; ct < 4; ct++) {
            float v = acc[rt][ct][reg];
            if (RELU) v = fmaxf(v, 0.f);
            C[(size_t)row * ldc + cg * 64 + ct * 16 + lrow] = v;
          }
        }
      }
    }
  } else {
    if (cg == 0 || cg == 3) {
      int cofs = (cg == 0) ? 0 : 64;
#pragma unroll
      for (int rt = 0; rt < 4; rt++) {
#pragma unroll
        for (int reg = 0; reg < 4; reg++) {
          int row = row0 + rt * 16 + quad * 4 + reg;
          if (row < M) {
#pragma unroll
            for (int ct = 0; ct < 4; ct++)
              qx[(size_t)row * 128 + cofs + ct * 16 + lrow] = acc[rt][ct][reg];
          }
        }
      }
    } else {
      int cofs = (cg == 1) ? 0 : 64;
#pragma unroll
      for (int rt = 0; rt < 4; rt++)
#pragma unroll
        for (int reg = 0; reg < 4; reg++) {
          int rloc = rt * 16 + quad * 4 + reg;
#pragma unroll
          for (int ct = 0; ct < 4; ct++)
            kvsh[rloc * 128 + cofs + ct * 16 + lrow] = __float2half(acc[rt][ct][reg]);
        }
    }
    __syncthreads();
    // repack kvsh -> interleaved kvb: [node][c4]{k4,v4} fp16, one uint4 each
    for (int idx = tid; idx < 1024; idx += 256) {
      int r = idx >> 4, c4 = idx & 15;
      int grow = row0 + r;
      if (grow < M) {
        uint2 kk = *(const uint2*)&kvsh[r * 128 + c4 * 4];
        uint2 vv = *(const uint2*)&kvsh[r * 128 + 64 + c4 * 4];
        uint4 o; o.x = kk.x; o.y = kk.y; o.z = vv.x; o.w = vv.y;
        *(uint4*)&kvb[(size_t)grow * 128 + c4 * 8] = o;
      }
    }
  }
}

// ---------------- fused attention + gate + LayerNorm ----------------

__global__ __launch_bounds__(256) void attn_post_kernel(
    const int* __restrict__ rowptr, const unsigned long long* __restrict__ edges,
    const float* __restrict__ qx, const uint4* __restrict__ kvb,
    const float* __restrict__ wedge, const float* __restrict__ wbeta,
    const float* __restrict__ lng, const float* __restrict__ lnb,
    float* __restrict__ h, int n)
{
  int lane = threadIdx.x & 63;
  int node = blockIdx.x * 4 + (threadIdx.x >> 6);
  if (node >= n) return;
  int grp = lane >> 4;
  int c4 = lane & 15;
  const float4* row4 = (const float4*)qx;
  float4 q4 = row4[(size_t)node * 32 + c4];
  float4 we4 = ((const float4*)wedge)[c4];
  const float SC = 0.25f * 1.44269504f;
  float4 qs;
  qs.x = q4.x * SC; qs.y = q4.y * SC; qs.z = q4.z * SC; qs.w = q4.w * SC;
  float qwe = qs.x * we4.x + qs.y * we4.y + qs.z * we4.z + qs.w * we4.w;
  int s0 = rowptr[node], s1 = rowptr[node + 1];
  float l = 0.f, pa = 0.f;
  float ax = 0.f, ay = 0.f, az = 0.f, aw = 0.f;
  for (int cb = s0; cb < s1; cb += 64) {
    int cnt = min(64, s1 - cb);
    unsigned long long rec64 = (lane < cnt) ? edges[cb + lane] : 0ull;
    unsigned int my_src = (unsigned int)(rec64 & 0xffffffffu);
    unsigned int my_ea  = (unsigned int)(rec64 >> 32);
    for (int j = 0; j * 4 < cnt; j++) {
      int sl = j * 4 + grp;
      bool valid = sl < cnt;
      int srcn   = (int)__shfl(my_src, sl);
      float a    = __uint_as_float(__shfl(my_ea, sl));
      uint4 kv = kvb[(size_t)srcn * 16 + c4];
      float2 k01 = __half22float2(*(__half2*)&kv.x);
      float2 k23 = __half22float2(*(__half2*)&kv.y);
      float2 v01 = __half22float2(*(__half2*)&kv.z);
      float2 v23 = __half22float2(*(__half2*)&kv.w);
      float prod = qs.x * k01.x + qs.y * k01.y + qs.z * k23.x + qs.w * k23.y
                 + a * qwe;
      prod += __shfl_xor(prod, 1);
      prod += __shfl_xor(prod, 2);
      float p = valid ? exp2f(prod) : 0.f;
      l  += p;
      pa += p * a;
      ax += p * v01.x;
      ay += p * v01.y;
      az += p * v23.x;
      aw += p * v23.y;
    }
  }
  ax += pa * we4.x; ay += pa * we4.y; az += pa * we4.z; aw += pa * we4.w;
  ax += __shfl_xor(ax, 16); ax += __shfl_xor(ax, 32);
  ay += __shfl_xor(ay, 16); ay += __shfl_xor(ay, 32);
  az += __shfl_xor(az, 16); az += __shfl_xor(az, 32);
  aw += __shfl_xor(aw, 16); aw += __shfl_xor(aw, 32);
  l  += __shfl_xor(l, 16);  l  += __shfl_xor(l, 32);
  float inv = 1.f / (l + 1e-16f);
  float ox = ax * inv, oy = ay * inv, oz = az * inv, ow = aw * inv;
  float4 xr = row4[(size_t)node * 32 + 16 + c4];
  float4 hr = ((const float4*)h)[(size_t)node * 16 + c4];
  float4 w1 = ((const float4*)wbeta)[c4];
  float4 w2 = ((const float4*)wbeta)[16 + c4];
  float4 w3 = ((const float4*)wbeta)[32 + c4];
  float sv = ox * w1.x + oy * w1.y + oz * w1.z + ow * w1.w
           + xr.x * w2.x + xr.y * w2.y + xr.z * w2.z + xr.w * w2.w
           + (ox - xr.x) * w3.x + (oy - xr.y) * w3.y
           + (oz - xr.z) * w3.z + (ow - xr.w) * w3.w;
  sv += __shfl_xor(sv, 1); sv += __shfl_xor(sv, 2);
  sv += __shfl_xor(sv, 4); sv += __shfl_xor(sv, 8);
  float beta = 1.f / (1.f + __expf(-sv));
  float zx = beta * xr.x + (1.f - beta) * ox + hr.x;
  float zy = beta * xr.y + (1.f - beta) * oy + hr.y;
  float zz = beta * xr.z + (1.f - beta) * oz + hr.z;
  float zw = beta * xr.w + (1.f - beta) * ow + hr.w;
  float mu = zx + zy + zz + zw;
  mu += __shfl_xor(mu, 1); mu += __shfl_xor(mu, 2);
  mu += __shfl_xor(mu, 4); mu += __shfl_xor(mu, 8);
  mu *= (1.f / 64.f);
  float dx = zx - mu, dy = zy - mu, dz = zz - mu, dw = zw - mu;
  float var = dx * dx + dy * dy + dz * dz + dw * dw;
  var += __shfl_xor(var, 1); var += __shfl_xor(var, 2);
  var += __shfl_xor(var, 4); var += __shfl_xor(var, 8);
  var *= (1.f / 64.f);
  float rstd = rsqrtf(var + LN_EPS);
  float4 g4 = ((const float4*)lng)[c4];
  float4 b4 = ((const float4*)lnb)[c4];
  if (grp == 0) {
    float4 res;
    res.x = dx * rstd * g4.x + b4.x;
    res.y = dy * rstd * g4.y + b4.y;
    res.z = dz * rstd * g4.z + b4.z;
    res.w = dw * rstd * g4.w + b4.w;
    ((float4*)h)[(size_t)node * 16 + c4] = res;
  }
}

// ---------------- classifier stage 2: out = h1 @ Wc2 + bc2 ----------------

__global__ __launch_bounds__(256) void cls2_kernel(const float* __restrict__ h1,
    const float* __restrict__ Wc2, const float* __restrict__ bc2,
    float* __restrict__ out, int n) {
  __shared__ float W2[HID * NC];
  __shared__ float b2[NC];
  int tid = threadIdx.x;
  for (int i = tid; i < HID * NC; i += 256) W2[i] = Wc2[i];
  if (tid < NC) b2[tid] = bc2[tid];
  __syncthreads();
  int row = blockIdx.x * 256 + tid;
  if (row >= n) return;
  float a[NC];
#pragma unroll
  for (int mm = 0; mm < NC; mm++) a[mm] = b2[mm];
  const float4* hp = (const float4*)(h1 + (size_t)row * HID);
#pragma unroll
  for (int k4 = 0; k4 < 16; k4++) {
    float4 hv = hp[k4];
    float h_[4] = {hv.x, hv.y, hv.z, hv.w};
#pragma unroll
    for (int kk = 0; kk < 4; kk++)
#pragma unroll
      for (int mm = 0; mm < NC; mm++)
        a[mm] = fmaf(h_[kk], W2[(k4 * 4 + kk) * NC + mm], a[mm]);
  }
#pragma unroll
  for (int mm = 0; mm < NC; mm++) out[(size_t)row * NC + mm] = a[mm];
}

// ---------------- launch ----------------

extern "C" void kernel_launch(void* const* d_in, const int* in_sizes, int n_in,
                              void* d_out, int out_size, void* d_ws, size_t ws_size,
                              hipStream_t stream) {
  const float* x     = (const float*)d_in[0];
  const int*   eidx  = (const int*)d_in[1];
  const float* eattr = (const float*)d_in[2];
  const float* Win   = (const float*)d_in[3];
  const float* b_in  = (const float*)d_in[4];
  const float* Wq    = (const float*)d_in[5];
  const float* bq    = (const float*)d_in[6];
  const float* Wk    = (const float*)d_in[7];
  const float* bk    = (const float*)d_in[8];
  const float* Wv    = (const float*)d_in[9];
  const float* bv    = (const float*)d_in[10];
  const float* Wedge = (const float*)d_in[11];
  const float* Wskip = (const float*)d_in[12];
  const float* bskip = (const float*)d_in[13];
  const float* Wbeta = (const float*)d_in[14];
  const float* ln_g  = (const float*)d_in[15];
  const float* ln_b  = (const float*)d_in[16];
  const float* Wc1   = (const float*)d_in[17];
  const float* bc1   = (const float*)d_in[18];
  const float* Wc2   = (const float*)d_in[19];
  const float* bc2   = (const float*)d_in[20];
  float* out = (float*)d_out;

  int n = in_sizes[0] / IN_F;   // 50000
  int e = in_sizes[2];          // 800000
  const int* src = eidx;
  const int* dstp = eidx + e;

  char* ws = (char*)d_ws;
  size_t off = 0;
  auto alloc = [&](size_t bytes) { void* p = ws + off; off += (bytes + 255) & ~(size_t)255; return p; };
  int*    rowptr = (int*)alloc((size_t)(n + 1) * 4);
  int*    fill   = (int*)alloc((size_t)n * 4);
  int*    part   = (int*)alloc(64 * 4);
  int*    cursor = (int*)alloc(256 * 4);
  unsigned long long* rec_stage = (unsigned long long*)alloc((size_t)e * 8);
  unsigned short*     dloc_stage = (unsigned short*)alloc((size_t)e * 2);
  unsigned long long* edges = (unsigned long long*)alloc((size_t)e * 8);
  float*  h      = (float*)alloc((size_t)n * HID * 4);
  float*  qx     = (float*)alloc((size_t)n * 128 * 4);
  __half* kvb    = (__half*)alloc((size_t)n * 128 * 2);
  float*  h1     = (float*)alloc((size_t)n * HID * 4);
  _Float16* Wt   = (_Float16*)alloc((size_t)896 * 64 * 2);
  float*  biasP  = (float*)alloc(896 * 4);

  int nb  = (n + 1023) / 1024;        // 49 scan chunks
  int nbk = (n + BSZ - 1) / BSZ;      // 196 buckets
  int mtiles = (n + 63) / 64;         // 782

  wprep_kernel<<<(896 * 64 + 255) / 256, 256, 0, stream>>>(
      Wq, Wk, Wv, Wskip, Wc1, Win, bq, bk, bv, bskip, bc1, b_in, Wt, biasP);

  (void)hipMemsetAsync(fill, 0, (size_t)n * 4, stream);
  count_kernel<<<(e + 255) / 256, 256, 0, stream>>>(dstp, fill, e);
  scan_reduce_kernel<<<nb, 256, 0, stream>>>(fill, part, n);
  scan_part_kernel<<<1, 64, 0, stream>>>(part, nb, rowptr + n);
  scan_apply_kernel<<<nb, 256, 0, stream>>>(fill, part, rowptr, n);
  cursor_init_kernel<<<1, 256, 0, stream>>>(rowptr, cursor, n, nbk);
  bucket_kernel<<<(e + CHUNK - 1) / CHUNK, 256, 0, stream>>>(
      src, dstp, eattr, cursor, rec_stage, dloc_stage, e);
  size_t psmem = (size_t)PCAP * 8 + BSZ * 8;
  place_kernel<<<nbk, 256, psmem, stream>>>(rowptr, rec_stage, dloc_stage, edges, n);

  // h = x @ Win + b_in   (K padded 50->64 in Wt/staging)
  gemm_mfma<1, 0, false><<<mtiles, 256, 0, stream>>>(
      x, IN_F, IN_F, n, Wt + (size_t)832 * 64, biasP + 832, h, HID, nullptr, nullptr);

  for (int i = 0; i < 3; i++) {
    gemm_mfma<4, 1, false><<<mtiles, 256, 0, stream>>>(
        h, HID, HID, n, Wt + (size_t)i * 256 * 64, biasP + i * 256,
        nullptr, 0, qx, kvb);
    attn_post_kernel<<<(n + 3) / 4, 256, 0, stream>>>(
        rowptr, edges, qx, (const uint4*)kvb, Wedge + i * HID, Wbeta + i * 3 * HID,
        ln_g + i * HID, ln_b + i * HID, h, n);
  }

  gemm_mfma<1, 0, true><<<mtiles, 256, 0, stream>>>(
      h, HID, HID, n, Wt + (size_t)768 * 64, biasP + 768, h1, HID, nullptr, nullptr);
  cls2_kernel<<<(n + 255) / 256, 256, 0, stream>>>(h1, Wc2, bc2, out, n);
}

// Round 10
// 339.958 us; speedup vs baseline: 1.4905x; 1.1179x over previous
//
#include <hip/hip_runtime.h>
#include <hip/hip_fp16.h>
#include <math.h>

#define IN_F 50
#define HID 64
#define NC 12
#define LN_EPS 1e-5f

// Bucketed CSR build parameters
#define BSH 8                 // bucket = dst >> 8 (256 nodes/bucket)
#define BSZ 256
#define NBK_MAX 256
#define CHUNK 8192            // edges per bucket-phase block
#define PCAP 8192             // per-bucket region capacity (mean 4096, +64 sigma)

#define SCQ 0.36067376022224085f   // 0.25 * log2(e)

typedef _Float16 half8 __attribute__((ext_vector_type(8)));
typedef _Float16 half4_t __attribute__((ext_vector_type(4)));
typedef _Float16 half2_t __attribute__((ext_vector_type(2)));
typedef float float4v __attribute__((ext_vector_type(4)));

static __device__ __forceinline__ half2_t h2cast(unsigned int u) {
  return __builtin_bit_cast(half2_t, u);
}

#if __has_builtin(__builtin_amdgcn_fdot2)
#define FDOT2(a, b, c) __builtin_amdgcn_fdot2((a), (b), (c), false)
#else
static __device__ __forceinline__ float FDOT2(half2_t a, half2_t b, float c) {
  return (float)a[0] * (float)b[0] + (float)a[1] * (float)b[1] + c;
}
#endif

// ---------------- CSR construction (bucketed counting sort) ----------------
// Phase B: scatter edges into per-bucket regions rec_stage[b*PCAP ...].
// cursor[b] ends up holding bucket b's edge count.

__global__ __launch_bounds__(256) void bucket_kernel(
    const int* __restrict__ src, const int* __restrict__ dst,
    const float* __restrict__ ea, int* __restrict__ cursor,
    unsigned long long* __restrict__ rec_stage,
    unsigned short* __restrict__ dloc_stage, int e)
{
  __shared__ int bcnt[256];
  __shared__ int gbase[256];
  __shared__ int bfill[256];
  int tid = threadIdx.x;
  bcnt[tid] = 0; bfill[tid] = 0;
  __syncthreads();
  int cb = blockIdx.x * CHUNK;
  int ce = min(cb + CHUNK, e);
  for (int i = cb + tid; i < ce; i += 256)
    atomicAdd(&bcnt[dst[i] >> BSH], 1);
  __syncthreads();
  if (bcnt[tid] > 0) gbase[tid] = atomicAdd(&cursor[tid], bcnt[tid]);
  __syncthreads();
  for (int i = cb + tid; i < ce; i += 256) {
    int d = dst[i];
    int b = d >> BSH;
    int slot = atomicAdd(&bfill[b], 1);
    size_t pos = (size_t)b * PCAP + gbase[b] + slot;
    rec_stage[pos] =
        ((unsigned long long)__float_as_uint(ea[i]) << 32) | (unsigned int)src[i];
    dloc_stage[pos] = (unsigned short)(d & (BSZ - 1));
  }
}

// exclusive scan over bucket counts (<=256, one block); writes bases + rowptr[n]
__global__ __launch_bounds__(256) void scanb_kernel(
    const int* __restrict__ cursor, int* __restrict__ bbase,
    int* __restrict__ rowptr_n, int nbk)
{
  int t = threadIdx.x;
  int v = (t < nbk) ? cursor[t] : 0;
  int incl = v;
#pragma unroll
  for (int off = 1; off < 64; off <<= 1) {
    int tv = __shfl_up(incl, off);
    if ((t & 63) >= off) incl += tv;
  }
  __shared__ int ws[4];
  if ((t & 63) == 63) ws[t >> 6] = incl;
  __syncthreads();
  int wb = 0;
  int w = t >> 6;
#pragma unroll
  for (int j = 0; j < 4; j++) if (j < w) wb += ws[j];
  int excl = incl - v + wb;
  if (t < nbk) bbase[t] = excl;
  if (t == 255) *rowptr_n = excl;   // total (v==0 past nbk)
}

// Phase C: per-bucket exact CSR placement; also writes rowptr for its nodes.
__global__ __launch_bounds__(256) void place_kernel(
    const int* __restrict__ cursor, const int* __restrict__ bbase,
    const unsigned long long* __restrict__ rec_stage,
    const unsigned short* __restrict__ dloc_stage,
    unsigned long long* __restrict__ edges, int* __restrict__ rowptr, int n)
{
  extern __shared__ char smem[];
  unsigned long long* sbuf = (unsigned long long*)smem;       // PCAP*8
  int* hist = (int*)(smem + (size_t)PCAP * 8);                // 256
  int* lcnt = hist + 256;                                     // 256
  __shared__ int ws[4];
  int b = blockIdx.x;
  int t = threadIdx.x;
  int lo = b * BSZ;
  int hi = min(lo + BSZ, n);
  int cnt  = cursor[b];
  int base = bbase[b];
  size_t bofs = (size_t)b * PCAP;
  hist[t] = 0;
  __syncthreads();
  for (int i = t; i < cnt; i += 256)
    atomicAdd(&hist[dloc_stage[bofs + i]], 1);
  __syncthreads();
  int v = hist[t];
  int incl = v;
#pragma unroll
  for (int off = 1; off < 64; off <<= 1) {
    int tv = __shfl_up(incl, off);
    if ((t & 63) >= off) incl += tv;
  }
  if ((t & 63) == 63) ws[t >> 6] = incl;
  __syncthreads();
  int wb = 0;
  int w = t >> 6;
#pragma unroll
  for (int j = 0; j < 4; j++) if (j < w) wb += ws[j];
  int excl = incl - v + wb;
  if (lo + t < hi) rowptr[lo + t] = base + excl;
  lcnt[t] = excl;
  __syncthreads();
  for (int i = t; i < cnt; i += 256) {
    unsigned long long rec = rec_stage[bofs + i];
    int dl = dloc_stage[bofs + i];
    int slot = atomicAdd(&lcnt[dl], 1);
    sbuf[slot] = rec;
  }
  __syncthreads();
  for (int i = t; i < cnt; i += 256)
    edges[(size_t)base + i] = sbuf[i];
}

// ---------------- weight prep: fp16 transposed Wt[col][k] + packed bias ----------------
// col layout: 0..767 = layer l (256 each: q|k|v|skip x 64), 768..831 = Wc1, 832..895 = Win

__global__ __launch_bounds__(256) void wprep_kernel(
    const float* __restrict__ Wq, const float* __restrict__ Wk,
    const float* __restrict__ Wv, const float* __restrict__ Ws,
    const float* __restrict__ Wc1, const float* __restrict__ Win,
    const float* __restrict__ bq, const float* __restrict__ bk,
    const float* __restrict__ bv, const float* __restrict__ bs,
    const float* __restrict__ bc1, const float* __restrict__ bin,
    _Float16* __restrict__ Wt, float* __restrict__ biasP)
{
  int idx = blockIdx.x * 256 + threadIdx.x;
  if (idx >= 896 * 64) return;
  int col = idx >> 6, k = idx & 63;
  float w, b;
  if (col < 768) {
    int l = col >> 8, rem = col & 255;
    int mat = rem >> 6, c = rem & 63;
    const float* W  = (mat == 0) ? Wq : (mat == 1) ? Wk : (mat == 2) ? Wv : Ws;
    const float* bb = (mat == 0) ? bq : (mat == 1) ? bk : (mat == 2) ? bv : bs;
    w = W[((size_t)l * 64 + k) * 64 + c];
    b = bb[l * 64 + c];
  } else if (col < 832) {
    int c = col - 768;
    w = Wc1[k * 64 + c];
    b = bc1[c];
  } else {
    int c = col - 832;
    w = (k < IN_F) ? Win[k * 64 + c] : 0.f;
    b = bin[c];
  }
  Wt[idx] = (_Float16)w;
  if (k == 0) biasP[col] = b;
}

// ---------------- MFMA GEMM ----------------
// MODE=1 (layer): wave m = matrix m (q,k,v,xr). q (pre-scaled by SCQ) and xr ->
// fp16 qxh[node][128] via LDS transpose; k/v -> fp16 interleaved kvb.
// MODE=0: plain fp32 C (+RELU).

template<int NMAT, int MODE, bool RELU>
__global__ __launch_bounds__(256) void gemm_mfma(
    const float* __restrict__ A, int lda, int kin, int M,
    const _Float16* __restrict__ Wt, const float* __restrict__ biasP,
    float* __restrict__ C, int ldc,
    __half* __restrict__ qxh, __half* __restrict__ kvb)
{
  __shared__ __align__(16) _Float16 hsh[64 * 72];
  constexpr int KVSZ = (MODE == 1) ? 64 * 128 : 8;
  __shared__ __align__(16) __half kvsh[KVSZ];
  __shared__ __align__(16) __half qxsh[KVSZ];

  const int tid = threadIdx.x;
  const int wave = tid >> 6, lane = tid & 63;
  const int lrow = lane & 15, quad = lane >> 4;
  const int row0 = blockIdx.x * 64;
  constexpr int WPC = 4 / NMAT;
  const int cg = wave / WPC;
  const int wi = wave % WPC;

  half8 bf[4][2];
  const _Float16* wbase = Wt + (size_t)cg * 64 * 64;
#pragma unroll
  for (int ct = 0; ct < 4; ct++)
#pragma unroll
    for (int ks = 0; ks < 2; ks++)
      bf[ct][ks] = *(const half8*)&wbase[(ct * 16 + lrow) * 64 + ks * 32 + quad * 8];
  float bv_[4];
#pragma unroll
  for (int ct = 0; ct < 4; ct++) bv_[ct] = biasP[cg * 64 + ct * 16 + lrow];

  if (kin == 64) {
    int r = tid >> 2, cq = tid & 3;
    int grow = row0 + r;
#pragma unroll
    for (int i = 0; i < 4; i++) {
      int c0 = cq * 16 + i * 4;
      float4 v = make_float4(0.f, 0.f, 0.f, 0.f);
      if (grow < M) v = *(const float4*)&A[(size_t)grow * lda + c0];
      half4_t hv;
      hv[0] = (_Float16)v.x; hv[1] = (_Float16)v.y;
      hv[2] = (_Float16)v.z; hv[3] = (_Float16)v.w;
      *(half4_t*)&hsh[r * 72 + c0] = hv;
    }
  } else {
    for (int idx = tid; idx < 64 * 64; idx += 256) {
      int r = idx >> 6, c = idx & 63;
      int grow = row0 + r;
      float v = (grow < M && c < kin) ? A[(size_t)grow * lda + c] : 0.f;
      hsh[r * 72 + c] = (_Float16)v;
    }
  }
  __syncthreads();

  float4v acc[NMAT][4];
#pragma unroll
  for (int rt = 0; rt < NMAT; rt++)
#pragma unroll
    for (int ct = 0; ct < 4; ct++) {
      acc[rt][ct][0] = bv_[ct]; acc[rt][ct][1] = bv_[ct];
      acc[rt][ct][2] = bv_[ct]; acc[rt][ct][3] = bv_[ct];
    }

#pragma unroll
  for (int rt = 0; rt < NMAT; rt++) {
    int rbase = (wi * NMAT + rt) * 16;
#pragma unroll
    for (int ks = 0; ks < 2; ks++) {
      half8 af = *(const half8*)&hsh[(rbase + lrow) * 72 + ks * 32 + quad * 8];
#pragma unroll
      for (int ct = 0; ct < 4; ct++)
        acc[rt][ct] = __builtin_amdgcn_mfma_f32_16x16x32_f16(af, bf[ct][ks],
                                                             acc[rt][ct], 0, 0, 0);
    }
  }

  if (MODE == 0) {
#pragma unroll
    for (int rt = 0; rt < NMAT; rt++) {
      int rbase = (wi * NMAT + rt) * 16;
#pragma unroll
      for (int reg = 0; reg < 4; reg++) {
        int row = row0 + rbase + quad * 4 + reg;
        if (row < M) {
#pragma unroll
          for (int ct = 0; ct < 4; ct++) {
            float v = acc[rt][ct][reg];
            if (RELU) v = fmaxf(v, 0.f);
            C[(size_t)row * ldc + cg * 64 + ct * 16 + lrow] = v;
          }
        }
      }
    }
  } else {
    // stage into LDS transpose buffers: q (scaled) / xr -> qxsh, k / v -> kvsh
    __half* dstsh = (cg == 0 || cg == 3) ? qxsh : kvsh;
    int cofs = (cg == 0 || cg == 1) ? 0 : 64;
    float scale = (cg == 0) ? SCQ : 1.f;
#pragma unroll
    for (int rt = 0; rt < 4; rt++)
#pragma unroll
      for (int reg = 0; reg < 4; reg++) {
        int rloc = rt * 16 + quad * 4 + reg;
#pragma unroll
        for (int ct = 0; ct < 4; ct++)
          dstsh[rloc * 128 + cofs + ct * 16 + lrow] =
              __float2half(acc[rt][ct][reg] * scale);
      }
    __syncthreads();
    // kvb: [node][c4]{k4,v4} interleaved fp16
    for (int idx = tid; idx < 1024; idx += 256) {
      int r = idx >> 4, c4 = idx & 15;
      int grow = row0 + r;
      if (grow < M) {
        uint2 kk = *(const uint2*)&kvsh[r * 128 + c4 * 4];
        uint2 vv = *(const uint2*)&kvsh[r * 128 + 64 + c4 * 4];
        uint4 o; o.x = kk.x; o.y = kk.y; o.z = vv.x; o.w = vv.y;
        *(uint4*)&kvb[(size_t)grow * 128 + c4 * 8] = o;
      }
    }
    // qxh: [node][128 halfs] = qs(0:64) | xr(64:128), contiguous copy
    for (int idx = tid; idx < 1024; idx += 256) {
      int r = idx >> 4, g8 = idx & 15;
      int grow = row0 + r;
      if (grow < M)
        *(uint4*)&qxh[(size_t)grow * 128 + g8 * 8] =
            *(const uint4*)&qxsh[r * 128 + g8 * 8];
    }
  }
}

// ---------------- fused attention + gate + LayerNorm ----------------
// qxh: [node][128 halfs] = q*SCQ (0:64) | xr (64:128)
// kvb: [node][16 uint4]: c4 -> {k quad, v quad} fp16
// edges: 8B packed (ea<<32 | src)

__global__ __launch_bounds__(256) void attn_post_kernel(
    const int* __restrict__ rowptr, const unsigned long long* __restrict__ edges,
    const __half* __restrict__ qxh, const uint4* __restrict__ kvb,
    const float* __restrict__ wedge, const float* __restrict__ wbeta,
    const float* __restrict__ lng, const float* __restrict__ lnb,
    float* __restrict__ h, int n)
{
  int lane = threadIdx.x & 63;
  int node = blockIdx.x * 4 + (threadIdx.x >> 6);
  if (node >= n) return;
  int grp = lane >> 4;
  int c4 = lane & 15;
  const __half* qrow = qxh + (size_t)node * 128;
  uint2 qu = ((const uint2*)qrow)[c4];
  half2_t qh01 = h2cast(qu.x), qh23 = h2cast(qu.y);
  float qf0 = (float)qh01[0], qf1 = (float)qh01[1];
  float qf2 = (float)qh23[0], qf3 = (float)qh23[1];
  float4 we4 = ((const float4*)wedge)[c4];
  float qwe = qf0 * we4.x + qf1 * we4.y + qf2 * we4.z + qf3 * we4.w;
  int s0 = rowptr[node], s1 = rowptr[node + 1];
  float l = 0.f, pa = 0.f;
  float ax = 0.f, ay = 0.f, az = 0.f, aw = 0.f;
  for (int cb = s0; cb < s1; cb += 64) {
    int cnt = min(64, s1 - cb);
    unsigned long long rec64 = (lane < cnt) ? edges[cb + lane] : 0ull;
    unsigned int my_src = (unsigned int)(rec64 & 0xffffffffu);
    unsigned int my_ea  = (unsigned int)(rec64 >> 32);
#pragma unroll 2
    for (int j = 0; j * 4 < cnt; j++) {
      int sl = j * 4 + grp;
      bool valid = sl < cnt;
      int srcn   = (int)__shfl(my_src, sl);
      float a    = __uint_as_float(__shfl(my_ea, sl));
      uint4 kv = kvb[(size_t)srcn * 16 + c4];
      float prod = a * qwe;
      prod = FDOT2(qh01, h2cast(kv.x), prod);
      prod = FDOT2(qh23, h2cast(kv.y), prod);
      prod += __shfl_xor(prod, 1);
      prod += __shfl_xor(prod, 2);           // per-head 16-chan dot (log2 units)
      float p = valid ? exp2f(prod) : 0.f;
      half2_t v01 = h2cast(kv.z), v23 = h2cast(kv.w);
      l  += p;
      pa = fmaf(p, a, pa);
      ax = fmaf(p, (float)v01[0], ax);
      ay = fmaf(p, (float)v01[1], ay);
      az = fmaf(p, (float)v23[0], az);
      aw = fmaf(p, (float)v23[1], aw);
    }
  }
  ax += pa * we4.x; ay += pa * we4.y; az += pa * we4.z; aw += pa * we4.w;
  ax += __shfl_xor(ax, 16); ax += __shfl_xor(ax, 32);
  ay += __shfl_xor(ay, 16); ay += __shfl_xor(ay, 32);
  az += __shfl_xor(az, 16); az += __shfl_xor(az, 32);
  aw += __shfl_xor(aw, 16); aw += __shfl_xor(aw, 32);
  l  += __shfl_xor(l, 16);  l  += __shfl_xor(l, 32);
  float inv = 1.f / (l + 1e-16f);
  float ox = ax * inv, oy = ay * inv, oz = az * inv, ow = aw * inv;
  uint2 xu = ((const uint2*)(qrow + 64))[c4];
  half2_t x01 = h2cast(xu.x), x23 = h2cast(xu.y);
  float4 xr;
  xr.x = (float)x01[0]; xr.y = (float)x01[1];
  xr.z = (float)x23[0]; xr.w = (float)x23[1];
  float4 hr = ((const float4*)h)[(size_t)node * 16 + c4];
  float4 w1 = ((const float4*)wbeta)[c4];
  float4 w2 = ((const float4*)wbeta)[16 + c4];
  float4 w3 = ((const float4*)wbeta)[32 + c4];
  float sv = ox * w1.x + oy * w1.y + oz * w1.z + ow * w1.w
           + xr.x * w2.x + xr.y * w2.y + xr.z * w2.z + xr.w * w2.w
           + (ox - xr.x) * w3.x + (oy - xr.y) * w3.y
           + (oz - xr.z) * w3.z + (ow - xr.w) * w3.w;
  sv += __shfl_xor(sv, 1); sv += __shfl_xor(sv, 2);
  sv += __shfl_xor(sv, 4); sv += __shfl_xor(sv, 8);
  float beta = 1.f / (1.f + __expf(-sv));
  float zx = beta * xr.x + (1.f - beta) * ox + hr.x;
  float zy = beta * xr.y + (1.f - beta) * oy + hr.y;
  float zz = beta * xr.z + (1.f - beta) * oz + hr.z;
  float zw = beta * xr.w + (1.f - beta) * ow + hr.w;
  float mu = zx + zy + zz + zw;
  mu += __shfl_xor(mu, 1); mu += __shfl_xor(mu, 2);
  mu += __shfl_xor(mu, 4); mu += __shfl_xor(mu, 8);
  mu *= (1.f / 64.f);
  float dx = zx - mu, dy = zy - mu, dz = zz - mu, dw = zw - mu;
  float var = dx * dx + dy * dy + dz * dz + dw * dw;
  var += __shfl_xor(var, 1); var += __shfl_xor(var, 2);
  var += __shfl_xor(var, 4); var += __shfl_xor(var, 8);
  var *= (1.f / 64.f);
  float rstd = rsqrtf(var + LN_EPS);
  float4 g4 = ((const float4*)lng)[c4];
  float4 b4 = ((const float4*)lnb)[c4];
  if (grp == 0) {
    float4 res;
    res.x = dx * rstd * g4.x + b4.x;
    res.y = dy * rstd * g4.y + b4.y;
    res.z = dz * rstd * g4.z + b4.z;
    res.w = dw * rstd * g4.w + b4.w;
    ((float4*)h)[(size_t)node * 16 + c4] = res;
  }
}

// ---------------- classifier stage 2: out = h1 @ Wc2 + bc2 ----------------

__global__ __launch_bounds__(256) void cls2_kernel(const float* __restrict__ h1,
    const float* __restrict__ Wc2, const float* __restrict__ bc2,
    float* __restrict__ out, int n) {
  __shared__ float W2[HID * NC];
  __shared__ float b2[NC];
  int tid = threadIdx.x;
  for (int i = tid; i < HID * NC; i += 256) W2[i] = Wc2[i];
  if (tid < NC) b2[tid] = bc2[tid];
  __syncthreads();
  int row = blockIdx.x * 256 + tid;
  if (row >= n) return;
  float a[NC];
#pragma unroll
  for (int mm = 0; mm < NC; mm++) a[mm] = b2[mm];
  const float4* hp = (const float4*)(h1 + (size_t)row * HID);
#pragma unroll
  for (int k4 = 0; k4 < 16; k4++) {
    float4 hv = hp[k4];
    float h_[4] = {hv.x, hv.y, hv.z, hv.w};
#pragma unroll
    for (int kk = 0; kk < 4; kk++)
#pragma unroll
      for (int mm = 0; mm < NC; mm++)
        a[mm] = fmaf(h_[kk], W2[(k4 * 4 + kk) * NC + mm], a[mm]);
  }
#pragma unroll
  for (int mm = 0; mm < NC; mm++) out[(size_t)row * NC + mm] = a[mm];
}

// ---------------- launch ----------------

extern "C" void kernel_launch(void* const* d_in, const int* in_sizes, int n_in,
                              void* d_out, int out_size, void* d_ws, size_t ws_size,
                              hipStream_t stream) {
  const float* x     = (const float*)d_in[0];
  const int*   eidx  = (const int*)d_in[1];
  const float* eattr = (const float*)d_in[2];
  const float* Win   = (const float*)d_in[3];
  const float* b_in  = (const float*)d_in[4];
  const float* Wq    = (const float*)d_in[5];
  const float* bq    = (const float*)d_in[6];
  const float* Wk    = (const float*)d_in[7];
  const float* bk    = (const float*)d_in[8];
  const float* Wv    = (const float*)d_in[9];
  const float* bv    = (const float*)d_in[10];
  const float* Wedge = (const float*)d_in[11];
  const float* Wskip = (const float*)d_in[12];
  const float* bskip = (const float*)d_in[13];
  const float* Wbeta = (const float*)d_in[14];
  const float* ln_g  = (const float*)d_in[15];
  const float* ln_b  = (const float*)d_in[16];
  const float* Wc1   = (const float*)d_in[17];
  const float* bc1   = (const float*)d_in[18];
  const float* Wc2   = (const float*)d_in[19];
  const float* bc2   = (const float*)d_in[20];
  float* out = (float*)d_out;

  int n = in_sizes[0] / IN_F;   // 50000
  int e = in_sizes[2];          // 800000
  const int* src = eidx;
  const int* dstp = eidx + e;

  char* ws = (char*)d_ws;
  size_t off = 0;
  auto alloc = [&](size_t bytes) { void* p = ws + off; off += (bytes + 255) & ~(size_t)255; return p; };
  int nbk = (n + BSZ - 1) / BSZ;      // 196 buckets

  int*    rowptr = (int*)alloc((size_t)(n + 1) * 4);
  int*    cursor = (int*)alloc(NBK_MAX * 4);
  int*    bbase  = (int*)alloc(NBK_MAX * 4);
  unsigned long long* rec_stage = (unsigned long long*)alloc((size_t)nbk * PCAP * 8);
  unsigned short*     dloc_stage = (unsigned short*)alloc((size_t)nbk * PCAP * 2);
  unsigned long long* edges = (unsigned long long*)alloc((size_t)e * 8);
  float*  h      = (float*)alloc((size_t)n * HID * 4);
  __half* qxh    = (__half*)alloc((size_t)n * 128 * 2);
  __half* kvb    = (__half*)alloc((size_t)n * 128 * 2);
  float*  h1     = (float*)alloc((size_t)n * HID * 4);
  _Float16* Wt   = (_Float16*)alloc((size_t)896 * 64 * 2);
  float*  biasP  = (float*)alloc(896 * 4);

  int mtiles = (n + 63) / 64;         // 782

  wprep_kernel<<<(896 * 64 + 255) / 256, 256, 0, stream>>>(
      Wq, Wk, Wv, Wskip, Wc1, Win, bq, bk, bv, bskip, bc1, b_in, Wt, biasP);

  (void)hipMemsetAsync(cursor, 0, NBK_MAX * 4, stream);
  bucket_kernel<<<(e + CHUNK - 1) / CHUNK, 256, 0, stream>>>(
      src, dstp, eattr, cursor, rec_stage, dloc_stage, e);
  scanb_kernel<<<1, 256, 0, stream>>>(cursor, bbase, rowptr + n, nbk);
  size_t psmem = (size_t)PCAP * 8 + 512 * 4;
  place_kernel<<<nbk, 256, psmem, stream>>>(
      cursor, bbase, rec_stage, dloc_stage, edges, rowptr, n);

  // h = x @ Win + b_in   (K padded 50->64 in Wt/staging)
  gemm_mfma<1, 0, false><<<mtiles, 256, 0, stream>>>(
      x, IN_F, IN_F, n, Wt + (size_t)832 * 64, biasP + 832, h, HID, nullptr, nullptr);

  for (int i = 0; i < 3; i++) {
    gemm_mfma<4, 1, false><<<mtiles, 256, 0, stream>>>(
        h, HID, HID, n, Wt + (size_t)i * 256 * 64, biasP + i * 256,
        nullptr, 0, qxh, kvb);
    attn_post_kernel<<<(n + 3) / 4, 256, 0, stream>>>(
        rowptr, edges, qxh, (const uint4*)kvb, Wedge + i * HID, Wbeta + i * 3 * HID,
        ln_g + i * HID, ln_b + i * HID, h, n);
  }

  gemm_mfma<1, 0, true><<<mtiles, 256, 0, stream>>>(
      h, HID, HID, n, Wt + (size_t)768 * 64, biasP + 768, h1, HID, nullptr, nullptr);
  cls2_kernel<<<(n + 255) / 256, 256, 0, stream>>>(h1, Wc2, bc2, out, n);
}